// Round 15
// baseline (44644.864 us; speedup 1.0000x reference)
//
#include <hip/hip_runtime.h>
#include <hip/hip_bf16.h>

// ROUND 15 = round-10/14 PASSING kernel + SHADOW exercise of the 4 suspect split-K GEMM
// kernels (verbatim R11 code, same grids) to bisect the R11-R13 abort.
// Shadow kernels read only valid final f32 data and write into out_pri's region,
// which the real prior phase then overwrites. Outputs are unaffected.

// ---------------- constants ----------------
constexpr int NB = 64;
constexpr int NT = 64;
constexpr int DET = 2048;
constexpr int SDIM = 1024;
constexpr int ACTD = 64;
constexpr int DPER = 256;
constexpr int COREIN = 1792;

constexpr size_t OS   = (size_t)NB * NT * DET;
constexpr size_t OPRI = OS + (size_t)NB * NT * SDIM;
constexpr size_t OPOST= OPRI + (size_t)NB * NT * SDIM;

__device__ __forceinline__ double silu_d(double v) { return v * (1.0 / (1.0 + exp(-v))); }
__device__ __forceinline__ float silu_f(float v) { return v / (1.0f + expf(-v)); }
__device__ __forceinline__ unsigned rotl32(unsigned x, int r) { return (x << r) | (x >> (32 - r)); }

// ---------------- JAX threefry2x32 gumbel, key(42), PARTITIONABLE XOR ----------------
__device__ double gumbel_d(int t, int b, int s, int c) {
  unsigned idx = ((unsigned)(t * NB + b) * 32u + (unsigned)s) * 32u + (unsigned)c;
  unsigned x0 = 0u, x1 = idx;
  const unsigned k0 = 0u, k1 = 42u, k2 = 0x1BD11BDAu ^ k0 ^ k1;
  x0 += k0; x1 += k1;
#define TFR(r) { x0 += x1; x1 = rotl32(x1, r); x1 ^= x0; }
  TFR(13) TFR(15) TFR(26) TFR(6)  x0 += k1; x1 += k2 + 1u;
  TFR(17) TFR(29) TFR(16) TFR(24) x0 += k2; x1 += k0 + 2u;
  TFR(13) TFR(15) TFR(26) TFR(6)  x0 += k0; x1 += k1 + 3u;
  TFR(17) TFR(29) TFR(16) TFR(24) x0 += k1; x1 += k2 + 4u;
  TFR(13) TFR(15) TFR(26) TFR(6)  x0 += k2; x1 += k0 + 5u;
#undef TFR
  unsigned bits = x0 ^ x1;
  float f = __uint_as_float((bits >> 9) | 0x3f800000u) - 1.0f;
  const float TINY = 1.17549435e-38f;
  float u = fmaxf(TINY, f + TINY);
  double g = -log(-log((double)u));
  return (double)(float)g;
}

// ---------------- f64 GEMM ----------------
template<int NACC>
__device__ __forceinline__ void gemm_bodyD(const double* __restrict__ A, int lda,
    const float* __restrict__ W, int ldw, const float* __restrict__ bias,
    double* __restrict__ C, int ldc, int K)
{
  constexpr int RPG = 8, KT = 64, RT = RPG * NACC;
  __shared__ double As[RT][KT];
  const int tid = threadIdx.x;
  const int o = blockIdx.x * 32 + (tid & 31);
  const int rg = tid >> 5;
  const int rbase = blockIdx.y * RT;
  double acc[NACC];
#pragma unroll
  for (int j = 0; j < NACC; ++j) acc[j] = 0.0;
  for (int k0 = 0; k0 < K; k0 += KT) {
#pragma unroll
    for (int idx = tid; idx < RT * KT; idx += 256) {
      int rr = idx / KT, kk = idx % KT;
      As[rr][kk] = A[(size_t)(rbase + rr) * lda + (size_t)(k0 + kk)];
    }
    __syncthreads();
#pragma unroll 4
    for (int kk = 0; kk < KT; ++kk) {
      double w = (double)W[(size_t)(k0 + kk) * ldw + o];
#pragma unroll
      for (int j = 0; j < NACC; ++j) acc[j] += As[rg + j * RPG][kk] * w;
    }
    __syncthreads();
  }
  double bv = bias ? (double)bias[o] : 0.0;
#pragma unroll
  for (int j = 0; j < NACC; ++j) {
    int r = rbase + rg + j * RPG;
    C[(size_t)r * ldc + o] = acc[j] + bv;
  }
}

struct GDd { const double* A; const float* W; const float* bias; double* C; int lda; int K; };
__global__ __launch_bounds__(256) void gemm_x3D(GDd a, GDd b, GDd c) {
  GDd d = (blockIdx.z == 0) ? a : (blockIdx.z == 1) ? b : c;
  gemm_bodyD<2>(d.A, d.lda, d.W, 512, d.bias, d.C, 512, d.K);
}

__global__ __launch_bounds__(256) void gemm_q0D(
    const double* __restrict__ deter, const float* __restrict__ tokens,
    const float* __restrict__ w_q0, const float* __restrict__ b_q0,
    double* __restrict__ hq, int t)
{
  constexpr int KT = 64, RT = 16;
  __shared__ double As[RT][KT];
  const int tid = threadIdx.x;
  const int o = blockIdx.x * 32 + (tid & 31);
  const int rg = tid >> 5;
  const int rbase = blockIdx.y * RT;
  double acc[2] = {0.0, 0.0};
  for (int k0 = 0; k0 < DET + 512; k0 += KT) {
#pragma unroll
    for (int idx = tid; idx < RT * KT; idx += 256) {
      int rr = idx / KT, kk = idx % KT;
      int g = k0 + kk, b = rbase + rr;
      As[rr][kk] = (g < DET) ? deter[b * DET + g]
                             : (double)tokens[((size_t)(b * NT + t)) * 512 + (g - DET)];
    }
    __syncthreads();
#pragma unroll 4
    for (int kk = 0; kk < KT; ++kk) {
      double w = (double)w_q0[(size_t)(k0 + kk) * 512 + o];
      acc[0] += As[rg][kk] * w;
      acc[1] += As[rg + 8][kk] * w;
    }
    __syncthreads();
  }
  hq[(rbase + rg) * 512 + o]     = acc[0] + (double)b_q0[o];
  hq[(rbase + rg + 8) * 512 + o] = acc[1] + (double)b_q0[o];
}

__global__ __launch_bounds__(256) void gemm_bhD(
    const double* __restrict__ deter, const double* __restrict__ comb,
    const float* __restrict__ Wh, const float* __restrict__ bh_bias,
    double* __restrict__ bh)
{
  constexpr int KT = 64, RT = 32;
  __shared__ double As[RT][KT];
  const int tid = threadIdx.x;
  const int o = blockIdx.x * 32 + (tid & 31);
  const int rg = tid >> 5;
  const int rbase = blockIdx.y * RT;
  const int k = rbase >> 6;
  const float* W = Wh + (size_t)k * COREIN * DPER;
  double acc[4] = {0, 0, 0, 0};
  for (int k0 = 0; k0 < COREIN; k0 += KT) {
#pragma unroll
    for (int idx = tid; idx < RT * KT; idx += 256) {
      int rr = idx / KT, kk = idx % KT;
      int b = (rbase + rr) & 63;
      int i = k0 + kk;
      As[rr][kk] = (i < DPER) ? deter[b * DET + k * DPER + i] : comb[b * 1536 + (i - DPER)];
    }
    __syncthreads();
#pragma unroll 4
    for (int kk = 0; kk < KT; ++kk) {
      double w = (double)W[(size_t)(k0 + kk) * DPER + o];
#pragma unroll
      for (int j = 0; j < 4; ++j) acc[j] += As[rg + j * 8][kk] * w;
    }
    __syncthreads();
  }
  double bv = (double)bh_bias[k * DPER + o];
#pragma unroll
  for (int j = 0; j < 4; ++j) {
    int b = (rbase + rg + j * 8) & 63;
    bh[b * DET + k * DPER + o] = acc[j] + bv;
  }
}

__global__ __launch_bounds__(256) void gemm_bgD(
    const double* __restrict__ xn, const float* __restrict__ Wg,
    const float* __restrict__ bg_bias, double* __restrict__ gates)
{
  constexpr int KT = 64, RT = 32;
  __shared__ double As[RT][KT];
  const int tid = threadIdx.x;
  const int o = blockIdx.x * 32 + (tid & 31);
  const int rg = tid >> 5;
  const int rbase = blockIdx.y * RT;
  const int k = rbase >> 6;
  const float* W = Wg + (size_t)k * DPER * 768;
  double acc[4] = {0, 0, 0, 0};
  for (int k0 = 0; k0 < DPER; k0 += KT) {
#pragma unroll
    for (int idx = tid; idx < RT * KT; idx += 256) {
      int rr = idx / KT, kk = idx % KT;
      int b = (rbase + rr) & 63;
      As[rr][kk] = xn[b * DET + k * DPER + k0 + kk];
    }
    __syncthreads();
#pragma unroll 4
    for (int kk = 0; kk < KT; ++kk) {
      double w = (double)W[(size_t)(k0 + kk) * 768 + o];
#pragma unroll
      for (int j = 0; j < 4; ++j) acc[j] += As[rg + j * 8][kk] * w;
    }
    __syncthreads();
  }
  double bv = (double)bg_bias[k * 768 + o];
#pragma unroll
  for (int j = 0; j < 4; ++j) {
    int b = (rbase + rg + j * 8) & 63;
    gates[b * 6144 + k * 768 + o] = acc[j] + bv;
  }
}

// ---------------- small kernels ----------------
__global__ void zero_initD(double* deter, double* stoch) {
  int i = blockIdx.x * 256 + threadIdx.x;
  for (int idx = i; idx < NB * DET; idx += gridDim.x * 256) deter[idx] = 0.0;
  for (int idx = i; idx < NB * SDIM; idx += gridDim.x * 256) stoch[idx] = 0.0;
}

__global__ void prepD(const float* __restrict__ actions,
                      int t, double* deter, double* stoch, double* act_buf) {
  int b = blockIdx.x, tid = threadIdx.x;
  bool first = (t == 0);
  if (first) {
    for (int i = tid; i < DET; i += 256) deter[b * DET + i] = 0.0;
    for (int i = tid; i < SDIM; i += 256) stoch[b * SDIM + i] = 0.0;
  }
  if (tid < ACTD) {
    double a = first ? 0.0 : (double)actions[(size_t)(b * NT + t) * ACTD + tid];
    act_buf[b * ACTD + tid] = a / fmax(fabs(a), 1.0);
  }
}

__global__ __launch_bounds__(256) void norm_combD(
    const double* __restrict__ t0, const double* __restrict__ t1, const double* __restrict__ t2,
    const float* __restrict__ s0, const float* __restrict__ s1, const float* __restrict__ s2,
    double* __restrict__ comb)
{
  int b = blockIdx.x, tid = threadIdx.x;
  __shared__ double red[4];
  const double EPS = (double)1e-8f;
  for (int part = 0; part < 3; ++part) {
    const double* src = part == 0 ? t0 : part == 1 ? t1 : t2;
    const float* sc   = part == 0 ? s0 : part == 1 ? s1 : s2;
    double v0 = src[b * 512 + tid];
    double v1 = src[b * 512 + 256 + tid];
    double ss = v0 * v0 + v1 * v1;
#pragma unroll
    for (int m = 1; m < 64; m <<= 1) ss += __shfl_xor(ss, m);
    if ((tid & 63) == 0) red[tid >> 6] = ss;
    __syncthreads();
    double rm = sqrt((red[0] + red[1] + red[2] + red[3]) / 512.0 + EPS);
    comb[b * 1536 + part * 512 + tid]       = silu_d(v0 / rm * (double)sc[tid]);
    comb[b * 1536 + part * 512 + 256 + tid] = silu_d(v1 / rm * (double)sc[256 + tid]);
    __syncthreads();
  }
}

__global__ __launch_bounds__(256) void norm_xnD(const double* __restrict__ bh,
                                                const float* __restrict__ snh,
                                                double* __restrict__ xn)
{
  int b = blockIdx.x, tid = threadIdx.x;
  __shared__ double red[4];
  const double EPS = (double)1e-8f;
  double v[8]; double ss = 0.0;
#pragma unroll
  for (int j = 0; j < 8; ++j) { v[j] = bh[b * DET + tid + 256 * j]; ss += v[j] * v[j]; }
#pragma unroll
  for (int m = 1; m < 64; m <<= 1) ss += __shfl_xor(ss, m);
  if ((tid & 63) == 0) red[tid >> 6] = ss;
  __syncthreads();
  double rm = sqrt((red[0] + red[1] + red[2] + red[3]) / 2048.0 + EPS);
#pragma unroll
  for (int j = 0; j < 8; ++j) {
    int o = tid + 256 * j;
    xn[b * DET + o] = silu_d(v[j] / rm * (double)snh[o]);
  }
}

__global__ __launch_bounds__(256) void updD(const double* __restrict__ gates,
    double* __restrict__ deter, float* __restrict__ dout, int t)
{
  int b = blockIdx.x, tid = threadIdx.x;
#pragma unroll
  for (int j = 0; j < 8; ++j) {
    int d = tid + j * 256;
    double gr = gates[b * 6144 + d];
    double gc = gates[b * 6144 + 2048 + d];
    double gu = gates[b * 6144 + 4096 + d];
    double r = 1.0 / (1.0 + exp(-gr));
    double cnd = tanh(r * gc);
    double u = 1.0 / (1.0 + exp(-(gu - 1.0)));
    double nd = u * cnd + (1.0 - u) * deter[b * DET + d];
    deter[b * DET + d] = nd;
    dout[(size_t)(b * NT + t) * DET + d] = (float)nd;
  }
}

__global__ __launch_bounds__(256) void q1_sampleD(
    const double* __restrict__ hq, const float* __restrict__ s_q0,
    const float* __restrict__ w_q1, const float* __restrict__ b_q1,
    double* __restrict__ stoch, float* __restrict__ out_s,
    float* __restrict__ out_post, int t)
{
  __shared__ double sh[8][512];
  __shared__ double ssr[8];
  const int tid = threadIdx.x;
  const int colbase = blockIdx.x * 128;
  const int rbase = blockIdx.y * 8;
  const int r_loc = tid >> 5, l32 = tid & 31;
  const int b = rbase + r_loc;
  const double EPS = (double)1e-8f;
  const double C099 = (double)0.99f;
  const double CUNI = (double)(float)0.0003125;
  {
    double ss = 0.0;
#pragma unroll
    for (int j = 0; j < 16; ++j) {
      double v = hq[b * 512 + l32 + j * 32];
      sh[r_loc][l32 + j * 32] = v;
      ss += v * v;
    }
#pragma unroll
    for (int m = 1; m < 32; m <<= 1) ss += __shfl_xor(ss, m);
    if (l32 == 0) ssr[r_loc] = ss;
  }
  __syncthreads();
  {
    double rm = sqrt(ssr[r_loc] / 512.0 + EPS);
#pragma unroll
    for (int j = 0; j < 16; ++j) {
      int o = l32 + j * 32;
      sh[r_loc][o] = silu_d(sh[r_loc][o] / rm * (double)s_q0[o]);
    }
  }
  __syncthreads();
  double acc[4] = {0, 0, 0, 0};
#pragma unroll 4
  for (int k = 0; k < 512; ++k) {
    double h = sh[r_loc][k];
#pragma unroll
    for (int j = 0; j < 4; ++j) acc[j] += h * (double)w_q1[(size_t)k * 1024 + colbase + j * 32 + l32];
  }
#pragma unroll
  for (int j = 0; j < 4; ++j) {
    int col = colbase + j * 32 + l32;
    double logit = acc[j] + (double)b_q1[col];
    out_post[(size_t)(b * NT + t) * SDIM + col] = (float)logit;
    double m = logit;
#pragma unroll
    for (int mm = 1; mm < 32; mm <<= 1) m = fmax(m, __shfl_xor(m, mm));
    double e = exp(logit - m);
    double s = e;
#pragma unroll
    for (int mm = 1; mm < 32; mm <<= 1) s += __shfl_xor(s, mm);
    double p = C099 * (e / s) + CUNI;
    int sgrp = col >> 5;
    double val = log(p) + gumbel_d(t, b, sgrp, l32);
    double bv = val; int bi = l32;
#pragma unroll
    for (int mm = 1; mm < 32; mm <<= 1) {
      double ov = __shfl_xor(bv, mm);
      int oi = __shfl_xor(bi, mm);
      if (ov > bv || (ov == bv && oi < bi)) { bv = ov; bi = oi; }
    }
    double ohv = (1.0 + p) - p;
    double oh = (bi == l32) ? ohv : 0.0;
    stoch[b * SDIM + col] = oh;
    out_s[(size_t)(b * NT + t) * SDIM + col] = (float)oh;
  }
}

// ================= SHADOW: verbatim R11 split-K GEMM kernels (suspects under test) =========
__global__ __launch_bounds__(256) void xpart(
    const float* __restrict__ deter, const float* __restrict__ stoch,
    const float* __restrict__ w_d, const float* __restrict__ w_s,
    float* __restrict__ p0, float* __restrict__ p1)
{
  __shared__ float As[16][256];
  const int z = blockIdx.z;
  const float* A; const float* W; float* out; int lda, c;
  if (z < 8) { A = deter; W = w_d; out = p0; lda = 2048; c = z; }
  else       { A = stoch; W = w_s; out = p1; lda = 1024; c = z - 8; }
  const int i0 = c * 256;
  const int tid = threadIdx.x;
  const int col = blockIdx.x * 64 + (tid & 63);
  const int rbase = blockIdx.y * 16;
#pragma unroll
  for (int idx = tid; idx < 16 * 256; idx += 256) {
    int rr = idx >> 8, kk = idx & 255;
    As[rr][kk] = A[(size_t)(rbase + rr) * lda + i0 + kk];
  }
  __syncthreads();
  const int rg4 = (tid >> 6) * 4;
  float acc[4] = {0, 0, 0, 0};
  for (int kk = 0; kk < 256; ++kk) {
    float w = W[(size_t)(i0 + kk) * 512 + col];
#pragma unroll
    for (int j = 0; j < 4; ++j) acc[j] += As[rg4 + j][kk] * w;
  }
#pragma unroll
  for (int j = 0; j < 4; ++j)
    out[(size_t)(c * 64 + rbase + rg4 + j) * 512 + col] = acc[j];
}

__global__ __launch_bounds__(256) void bhpart(
    const float* __restrict__ deter, const float* __restrict__ comb,
    const float* __restrict__ w_blk_h, float* __restrict__ part)
{
  __shared__ float As[16][256];
  const int c = blockIdx.z;
  const int i0 = c * 256;
  const int tid = threadIdx.x;
  const int colbase = blockIdx.x * 64;
  const int col = colbase + (tid & 63);
  const int k = colbase >> 8;
  const int dd = col & 255;
  const int rbase = blockIdx.y * 16;
#pragma unroll
  for (int idx = tid; idx < 16 * 256; idx += 256) {
    int rr = idx >> 8, kk = idx & 255;
    As[rr][kk] = (c == 0) ? deter[(size_t)(rbase + rr) * 2048 + k * 256 + kk]
                          : comb[(size_t)(rbase + rr) * 1536 + (i0 - 256) + kk];
  }
  __syncthreads();
  const float* W = w_blk_h + (size_t)k * 1792 * 256;
  const int rg4 = (tid >> 6) * 4;
  float acc[4] = {0, 0, 0, 0};
  for (int kk = 0; kk < 256; ++kk) {
    float w = W[(size_t)(i0 + kk) * 256 + dd];
#pragma unroll
    for (int j = 0; j < 4; ++j) acc[j] += As[rg4 + j][kk] * w;
  }
#pragma unroll
  for (int j = 0; j < 4; ++j)
    part[(size_t)(c * 64 + rbase + rg4 + j) * 2048 + col] = acc[j];
}

__global__ __launch_bounds__(256) void q0part(
    const float* __restrict__ deter, const float* __restrict__ tokens,
    const float* __restrict__ w_q0, float* __restrict__ part, int t)
{
  __shared__ float As[16][256];
  const int c = blockIdx.z;
  const int i0 = c * 256;
  const int tid = threadIdx.x;
  const int col = blockIdx.x * 64 + (tid & 63);
  const int rbase = blockIdx.y * 16;
#pragma unroll
  for (int idx = tid; idx < 16 * 256; idx += 256) {
    int rr = idx >> 8, kk = idx & 255;
    As[rr][kk] = (c < 8) ? deter[(size_t)(rbase + rr) * 2048 + i0 + kk]
                         : tokens[((size_t)(rbase + rr) * NT + t) * 512 + (i0 - 2048) + kk];
  }
  __syncthreads();
  const int rg4 = (tid >> 6) * 4;
  float acc[4] = {0, 0, 0, 0};
  for (int kk = 0; kk < 256; ++kk) {
    float w = w_q0[(size_t)(i0 + kk) * 512 + col];
#pragma unroll
    for (int j = 0; j < 4; ++j) acc[j] += As[rg4 + j][kk] * w;
  }
#pragma unroll
  for (int j = 0; j < 4; ++j)
    part[(size_t)(c * 64 + rbase + rg4 + j) * 512 + col] = acc[j];
}

__global__ __launch_bounds__(256) void bgemm(
    const float* __restrict__ xn, const float* __restrict__ w_blk_g,
    const float* __restrict__ b_blk_g, float* __restrict__ gates)
{
  __shared__ float As[16][256];
  const int tid = threadIdx.x;
  const int colbase = blockIdx.x * 64;
  const int lane = tid & 63;
  const int k = colbase / 768;
  const int o = (colbase % 768) + lane;
  const int rbase = blockIdx.y * 16;
#pragma unroll
  for (int idx = tid; idx < 16 * 256; idx += 256) {
    int rr = idx >> 8, kk = idx & 255;
    As[rr][kk] = xn[(size_t)(rbase + rr) * 2048 + k * 256 + kk];
  }
  __syncthreads();
  const int rg4 = (tid >> 6) * 4;
  float acc[4] = {0, 0, 0, 0};
  for (int kk = 0; kk < 256; ++kk) {
    float w = w_blk_g[((size_t)k * 256 + kk) * 768 + o];
#pragma unroll
    for (int j = 0; j < 4; ++j) acc[j] += As[rg4 + j][kk] * w;
  }
  float bv = b_blk_g[k * 768 + o];
#pragma unroll
  for (int j = 0; j < 4; ++j)
    gates[(size_t)(rbase + rg4 + j) * 6144 + colbase + lane] = acc[j] + bv;
}

// ---------------- f32 prior path ----------------
template<int NACC>
__global__ __launch_bounds__(256) void gemm_k(const float* __restrict__ A, int lda,
    const float* __restrict__ W, int ldw, const float* __restrict__ bias,
    float* __restrict__ C, int ldc, int K)
{
  constexpr int RPG = 8, KT = 64, RT = RPG * NACC;
  __shared__ float As[RT][KT];
  const int tid = threadIdx.x;
  const int o = blockIdx.x * 32 + (tid & 31);
  const int rg = tid >> 5;
  const int rbase = blockIdx.y * RT;
  float acc[NACC];
#pragma unroll
  for (int j = 0; j < NACC; ++j) acc[j] = 0.0f;
  for (int k0 = 0; k0 < K; k0 += KT) {
#pragma unroll
    for (int idx = tid; idx < RT * KT; idx += 256) {
      int rr = idx / KT, kk = idx % KT;
      As[rr][kk] = A[(size_t)(rbase + rr) * lda + (size_t)(k0 + kk)];
    }
    __syncthreads();
#pragma unroll 8
    for (int kk = 0; kk < KT; ++kk) {
      float w = W[(size_t)(k0 + kk) * ldw + o];
#pragma unroll
      for (int j = 0; j < NACC; ++j) acc[j] += As[rg + j * RPG][kk] * w;
    }
    __syncthreads();
  }
  float bv = bias ? bias[o] : 0.0f;
#pragma unroll
  for (int j = 0; j < NACC; ++j) {
    int r = rbase + rg + j * RPG;
    C[(size_t)r * ldc + o] = acc[j] + bv;
  }
}

__global__ __launch_bounds__(256) void norm_h(const float* __restrict__ raw,
                                              const float* __restrict__ scale,
                                              float* __restrict__ outp)
{
  int r = blockIdx.x, tid = threadIdx.x;
  __shared__ float red[4];
  float v0 = raw[(size_t)r * 512 + tid];
  float v1 = raw[(size_t)r * 512 + 256 + tid];
  float ss = v0 * v0 + v1 * v1;
#pragma unroll
  for (int m = 1; m < 64; m <<= 1) ss += __shfl_xor(ss, m);
  if ((tid & 63) == 0) red[tid >> 6] = ss;
  __syncthreads();
  float rm = sqrtf((red[0] + red[1] + red[2] + red[3]) / 512.0f + 1e-8f);
  outp[(size_t)r * 512 + tid]       = silu_f(v0 / rm * scale[tid]);
  outp[(size_t)r * 512 + 256 + tid] = silu_f(v1 / rm * scale[256 + tid]);
}

// ---------------- launch ----------------
extern "C" void kernel_launch(void* const* d_in, const int* in_sizes, int n_in,
                              void* d_out, int out_size, void* d_ws, size_t ws_size,
                              hipStream_t stream)
{
  const float* tokens     = (const float*)d_in[0];
  const float* actions    = (const float*)d_in[1];
  const float* w_in_deter = (const float*)d_in[3];
  const float* b_in_deter = (const float*)d_in[4];
  const float* w_in_stoch = (const float*)d_in[5];
  const float* b_in_stoch = (const float*)d_in[6];
  const float* w_in_act   = (const float*)d_in[7];
  const float* b_in_act   = (const float*)d_in[8];
  const float* s_n0 = (const float*)d_in[9];
  const float* s_n1 = (const float*)d_in[10];
  const float* s_n2 = (const float*)d_in[11];
  const float* w_blk_h = (const float*)d_in[12];
  const float* b_blk_h = (const float*)d_in[13];
  const float* s_nh = (const float*)d_in[14];
  const float* w_blk_g = (const float*)d_in[15];
  const float* b_blk_g = (const float*)d_in[16];
  const float* w_p0 = (const float*)d_in[17];
  const float* b_p0 = (const float*)d_in[18];
  const float* s_p0 = (const float*)d_in[19];
  const float* w_p1 = (const float*)d_in[20];
  const float* b_p1 = (const float*)d_in[21];
  const float* s_p1 = (const float*)d_in[22];
  const float* w_p2 = (const float*)d_in[23];
  const float* b_p2 = (const float*)d_in[24];
  const float* w_q0 = (const float*)d_in[25];
  const float* b_q0 = (const float*)d_in[26];
  const float* s_q0 = (const float*)d_in[27];
  const float* w_q1 = (const float*)d_in[28];
  const float* b_q1 = (const float*)d_in[29];

  double* dws = (double*)d_ws;
  double* deterD = dws;
  double* stochD = deterD + 131072;
  double* actD   = stochD + 65536;
  double* t0D    = actD + 4096;
  double* t1D    = t0D + 32768;
  double* t2D    = t1D + 32768;
  double* combD  = t2D + 32768;
  double* bhD    = combD + 98304;
  double* xnD    = bhD + 131072;
  double* gatesD = xnD + 131072;
  double* hqD    = gatesD + 393216;
  float* hp_a = (float*)dws;
  float* hp_b = (float*)(dws + 1085440);

  float* outf = (float*)d_out;
  float* out_d    = outf;
  float* out_s    = outf + OS;
  float* out_pri  = outf + OPRI;
  float* out_post = outf + OPOST;

  zero_initD<<<dim3(256), dim3(256), 0, stream>>>(deterD, stochD);

  for (int t = 0; t < NT; ++t) {
    prepD<<<dim3(NB), dim3(256), 0, stream>>>(actions, t, deterD, stochD, actD);
    GDd g0{deterD, w_in_deter, b_in_deter, t0D, DET, DET};
    GDd g1{stochD, w_in_stoch, b_in_stoch, t1D, SDIM, SDIM};
    GDd g2{actD, w_in_act, b_in_act, t2D, ACTD, ACTD};
    gemm_x3D<<<dim3(16, 4, 3), dim3(256), 0, stream>>>(g0, g1, g2);
    norm_combD<<<dim3(NB), dim3(256), 0, stream>>>(t0D, t1D, t2D, s_n0, s_n1, s_n2, combD);
    gemm_bhD<<<dim3(8, 16), dim3(256), 0, stream>>>(deterD, combD, w_blk_h, b_blk_h, bhD);
    norm_xnD<<<dim3(NB), dim3(256), 0, stream>>>(bhD, s_nh, xnD);
    gemm_bgD<<<dim3(24, 16), dim3(256), 0, stream>>>(xnD, w_blk_g, b_blk_g, gatesD);
    updD<<<dim3(NB), dim3(256), 0, stream>>>(gatesD, deterD, out_d, t);
    gemm_q0D<<<dim3(16, 4), dim3(256), 0, stream>>>(deterD, tokens, w_q0, b_q0, hqD, t);
    q1_sampleD<<<dim3(8, 8), dim3(256), 0, stream>>>(hqD, s_q0, w_q1, b_q1,
        stochD, out_s, out_post, t);
  }

  // ===== SHADOW exercise of the 4 suspect kernels (results overwritten by prior phase) ====
  {
    float* U    = out_pri;            // scratch: real prior overwrites this below
    float* p_x0 = U;                  // 262144
    float* p_x1 = U + 262144;         // 131072
    float* p_bh = U + 393216;         // 917504
    float* p_q0 = U + 1310720;        // 327680
    float* p_gt = U + 1638400;        // 393216  -> total 2031616 < 4194304
    // valid f32 inputs: out_d rows 0..63, out_s as [64][1024]/[64][1536] data, tokens, weights
    xpart<<<dim3(8, 4, 12), dim3(256), 0, stream>>>(out_d, out_s, w_in_deter, w_in_stoch, p_x0, p_x1);
    bhpart<<<dim3(32, 4, 7), dim3(256), 0, stream>>>(out_d, out_s, w_blk_h, p_bh);
    q0part<<<dim3(8, 4, 10), dim3(256), 0, stream>>>(out_d, tokens, w_q0, p_q0, 0);
    bgemm<<<dim3(96, 4), dim3(256), 0, stream>>>(out_d, w_blk_g, b_blk_g, p_gt);
  }

  // batched f32 prior from d_seq (overwrites the shadow scratch with real values)
  gemm_k<4><<<dim3(16, 128), dim3(256), 0, stream>>>(
      out_d, DET, w_p0, 512, b_p0, hp_a, 512, DET);
  norm_h<<<dim3(NB * NT), dim3(256), 0, stream>>>(hp_a, s_p0, hp_b);
  gemm_k<4><<<dim3(16, 128), dim3(256), 0, stream>>>(
      hp_b, 512, w_p1, 512, b_p1, hp_a, 512, 512);
  norm_h<<<dim3(NB * NT), dim3(256), 0, stream>>>(hp_a, s_p1, hp_b);
  gemm_k<4><<<dim3(32, 128), dim3(256), 0, stream>>>(
      hp_b, 512, w_p2, 1024, b_p2, out_pri, 1024, 512);
}

// Round 16
// 31051.736 us; speedup vs baseline: 1.4378x; 1.4378x over previous
//
#include <hip/hip_runtime.h>
#include <hip/hip_bf16.h>

// ROUND 16 = R10/R14 PASSING structure converted f64 -> f32 (same kernels, grids, layout).
// No new kernels; gumbel bit-values identical (f64 internal math, f32 rounding).

// ---------------- constants ----------------
constexpr int NB = 64;
constexpr int NT = 64;
constexpr int DET = 2048;
constexpr int SDIM = 1024;
constexpr int ACTD = 64;
constexpr int DPER = 256;
constexpr int COREIN = 1792;

constexpr size_t OS   = (size_t)NB * NT * DET;
constexpr size_t OPRI = OS + (size_t)NB * NT * SDIM;
constexpr size_t OPOST= OPRI + (size_t)NB * NT * SDIM;

__device__ __forceinline__ float silu_f(float v) { return v / (1.0f + expf(-v)); }
__device__ __forceinline__ unsigned rotl32(unsigned x, int r) { return (x << r) | (x >> (32 - r)); }

// ---------------- JAX threefry2x32 gumbel, key(42), partitionable XOR (verified R10) -------
__device__ float gumbel_f(int t, int b, int s, int c) {
  unsigned idx = ((unsigned)(t * NB + b) * 32u + (unsigned)s) * 32u + (unsigned)c;
  unsigned x0 = 0u, x1 = idx;
  const unsigned k0 = 0u, k1 = 42u, k2 = 0x1BD11BDAu ^ k0 ^ k1;
  x0 += k0; x1 += k1;
#define TFR(r) { x0 += x1; x1 = rotl32(x1, r); x1 ^= x0; }
  TFR(13) TFR(15) TFR(26) TFR(6)  x0 += k1; x1 += k2 + 1u;
  TFR(17) TFR(29) TFR(16) TFR(24) x0 += k2; x1 += k0 + 2u;
  TFR(13) TFR(15) TFR(26) TFR(6)  x0 += k0; x1 += k1 + 3u;
  TFR(17) TFR(29) TFR(16) TFR(24) x0 += k1; x1 += k2 + 4u;
  TFR(13) TFR(15) TFR(26) TFR(6)  x0 += k2; x1 += k0 + 5u;
#undef TFR
  unsigned bits = x0 ^ x1;                          // partitionable: lane0 ^ lane1
  float f = __uint_as_float((bits >> 9) | 0x3f800000u) - 1.0f;
  const float TINY = 1.17549435e-38f;
  float u = fmaxf(TINY, f + TINY);
  double g = -log(-log((double)u));                 // same values as the R10 passing run
  return (float)g;
}

// ---------------- f32 GEMM: C = f32dot(A, W) + bias (identical structure to R10) ----------
template<int NACC>
__device__ __forceinline__ void gemm_bodyF(const float* __restrict__ A, int lda,
    const float* __restrict__ W, int ldw, const float* __restrict__ bias,
    float* __restrict__ C, int ldc, int K)
{
  constexpr int RPG = 8, KT = 64, RT = RPG * NACC;
  __shared__ float As[RT][KT];
  const int tid = threadIdx.x;
  const int o = blockIdx.x * 32 + (tid & 31);
  const int rg = tid >> 5;
  const int rbase = blockIdx.y * RT;
  float acc[NACC];
#pragma unroll
  for (int j = 0; j < NACC; ++j) acc[j] = 0.0f;
  for (int k0 = 0; k0 < K; k0 += KT) {
#pragma unroll
    for (int idx = tid; idx < RT * KT; idx += 256) {
      int rr = idx / KT, kk = idx % KT;
      As[rr][kk] = A[(size_t)(rbase + rr) * lda + (size_t)(k0 + kk)];
    }
    __syncthreads();
#pragma unroll 8
    for (int kk = 0; kk < KT; ++kk) {
      float w = W[(size_t)(k0 + kk) * ldw + o];
#pragma unroll
      for (int j = 0; j < NACC; ++j) acc[j] += As[rg + j * RPG][kk] * w;
    }
    __syncthreads();
  }
  float bv = bias ? bias[o] : 0.0f;
#pragma unroll
  for (int j = 0; j < NACC; ++j) {
    int r = rbase + rg + j * RPG;
    C[(size_t)r * ldc + o] = acc[j] + bv;
  }
}

struct GDf { const float* A; const float* W; const float* bias; float* C; int lda; int K; };
__global__ __launch_bounds__(256) void gemm_x3F(GDf a, GDf b, GDf c) {
  GDf d = (blockIdx.z == 0) ? a : (blockIdx.z == 1) ? b : c;
  gemm_bodyF<2>(d.A, d.lda, d.W, 512, d.bias, d.C, 512, d.K);
}

// ---------------- q0: hq = [deter | tokens_t] @ w_q0 + b_q0 (f32, K=2560) ----------------
__global__ __launch_bounds__(256) void gemm_q0F(
    const float* __restrict__ deter, const float* __restrict__ tokens,
    const float* __restrict__ w_q0, const float* __restrict__ b_q0,
    float* __restrict__ hq, int t)
{
  constexpr int KT = 64, RT = 16;
  __shared__ float As[RT][KT];
  const int tid = threadIdx.x;
  const int o = blockIdx.x * 32 + (tid & 31);
  const int rg = tid >> 5;
  const int rbase = blockIdx.y * RT;
  float acc[2] = {0.0f, 0.0f};
  for (int k0 = 0; k0 < DET + 512; k0 += KT) {
#pragma unroll
    for (int idx = tid; idx < RT * KT; idx += 256) {
      int rr = idx / KT, kk = idx % KT;
      int g = k0 + kk, b = rbase + rr;
      As[rr][kk] = (g < DET) ? deter[b * DET + g]
                             : tokens[((size_t)(b * NT + t)) * 512 + (g - DET)];
    }
    __syncthreads();
#pragma unroll 8
    for (int kk = 0; kk < KT; ++kk) {
      float w = w_q0[(size_t)(k0 + kk) * 512 + o];
      acc[0] += As[rg][kk] * w;
      acc[1] += As[rg + 8][kk] * w;
    }
    __syncthreads();
  }
  hq[(rbase + rg) * 512 + o]     = acc[0] + b_q0[o];
  hq[(rbase + rg + 8) * 512 + o] = acc[1] + b_q0[o];
}

// ---------------- block_h (f32) ----------------
__global__ __launch_bounds__(256) void gemm_bhF(
    const float* __restrict__ deter, const float* __restrict__ comb,
    const float* __restrict__ Wh, const float* __restrict__ bh_bias,
    float* __restrict__ bh)
{
  constexpr int KT = 64, RT = 32;
  __shared__ float As[RT][KT];
  const int tid = threadIdx.x;
  const int o = blockIdx.x * 32 + (tid & 31);
  const int rg = tid >> 5;
  const int rbase = blockIdx.y * RT;
  const int k = rbase >> 6;
  const float* W = Wh + (size_t)k * COREIN * DPER;
  float acc[4] = {0, 0, 0, 0};
  for (int k0 = 0; k0 < COREIN; k0 += KT) {
#pragma unroll
    for (int idx = tid; idx < RT * KT; idx += 256) {
      int rr = idx / KT, kk = idx % KT;
      int b = (rbase + rr) & 63;
      int i = k0 + kk;
      As[rr][kk] = (i < DPER) ? deter[b * DET + k * DPER + i] : comb[b * 1536 + (i - DPER)];
    }
    __syncthreads();
#pragma unroll 8
    for (int kk = 0; kk < KT; ++kk) {
      float w = W[(size_t)(k0 + kk) * DPER + o];
#pragma unroll
      for (int j = 0; j < 4; ++j) acc[j] += As[rg + j * 8][kk] * w;
    }
    __syncthreads();
  }
  float bv = bh_bias[k * DPER + o];
#pragma unroll
  for (int j = 0; j < 4; ++j) {
    int b = (rbase + rg + j * 8) & 63;
    bh[b * DET + k * DPER + o] = acc[j] + bv;
  }
}

// ---------------- block_g (f32) ----------------
__global__ __launch_bounds__(256) void gemm_bgF(
    const float* __restrict__ xn, const float* __restrict__ Wg,
    const float* __restrict__ bg_bias, float* __restrict__ gates)
{
  constexpr int KT = 64, RT = 32;
  __shared__ float As[RT][KT];
  const int tid = threadIdx.x;
  const int o = blockIdx.x * 32 + (tid & 31);
  const int rg = tid >> 5;
  const int rbase = blockIdx.y * RT;
  const int k = rbase >> 6;
  const float* W = Wg + (size_t)k * DPER * 768;
  float acc[4] = {0, 0, 0, 0};
  for (int k0 = 0; k0 < DPER; k0 += KT) {
#pragma unroll
    for (int idx = tid; idx < RT * KT; idx += 256) {
      int rr = idx / KT, kk = idx % KT;
      int b = (rbase + rr) & 63;
      As[rr][kk] = xn[b * DET + k * DPER + k0 + kk];
    }
    __syncthreads();
#pragma unroll 8
    for (int kk = 0; kk < KT; ++kk) {
      float w = W[(size_t)(k0 + kk) * 768 + o];
#pragma unroll
      for (int j = 0; j < 4; ++j) acc[j] += As[rg + j * 8][kk] * w;
    }
    __syncthreads();
  }
  float bv = bg_bias[k * 768 + o];
#pragma unroll
  for (int j = 0; j < 4; ++j) {
    int b = (rbase + rg + j * 8) & 63;
    gates[b * 6144 + k * 768 + o] = acc[j] + bv;
  }
}

// ---------------- small kernels ----------------
__global__ void zero_initF(float* deter, float* stoch) {
  int i = blockIdx.x * 256 + threadIdx.x;
  for (int idx = i; idx < NB * DET; idx += gridDim.x * 256) deter[idx] = 0.0f;
  for (int idx = i; idx < NB * SDIM; idx += gridDim.x * 256) stoch[idx] = 0.0f;
}

// is_first true only at t==0 (verified pattern)
__global__ void prepF(const float* __restrict__ actions,
                      int t, float* deter, float* stoch, float* act_buf) {
  int b = blockIdx.x, tid = threadIdx.x;
  bool first = (t == 0);
  if (first) {
    for (int i = tid; i < DET; i += 256) deter[b * DET + i] = 0.0f;
    for (int i = tid; i < SDIM; i += 256) stoch[b * SDIM + i] = 0.0f;
  }
  if (tid < ACTD) {
    float a = first ? 0.0f : actions[(size_t)(b * NT + t) * ACTD + tid];
    act_buf[b * ACTD + tid] = a / fmaxf(fabsf(a), 1.0f);
  }
}

// rms(512)+silu (f32) -> comb[64][1536]
__global__ __launch_bounds__(256) void norm_combF(
    const float* __restrict__ t0, const float* __restrict__ t1, const float* __restrict__ t2,
    const float* __restrict__ s0, const float* __restrict__ s1, const float* __restrict__ s2,
    float* __restrict__ comb)
{
  int b = blockIdx.x, tid = threadIdx.x;
  __shared__ float red[4];
  for (int part = 0; part < 3; ++part) {
    const float* src = part == 0 ? t0 : part == 1 ? t1 : t2;
    const float* sc  = part == 0 ? s0 : part == 1 ? s1 : s2;
    float v0 = src[b * 512 + tid];
    float v1 = src[b * 512 + 256 + tid];
    float ss = v0 * v0 + v1 * v1;
#pragma unroll
    for (int m = 1; m < 64; m <<= 1) ss += __shfl_xor(ss, m);
    if ((tid & 63) == 0) red[tid >> 6] = ss;
    __syncthreads();
    float rm = sqrtf((red[0] + red[1] + red[2] + red[3]) / 512.0f + 1e-8f);
    comb[b * 1536 + part * 512 + tid]       = silu_f(v0 / rm * sc[tid]);
    comb[b * 1536 + part * 512 + 256 + tid] = silu_f(v1 / rm * sc[256 + tid]);
    __syncthreads();
  }
}

// rms(2048)+silu (f32) -> xn
__global__ __launch_bounds__(256) void norm_xnF(const float* __restrict__ bh,
                                                const float* __restrict__ snh,
                                                float* __restrict__ xn)
{
  int b = blockIdx.x, tid = threadIdx.x;
  __shared__ float red[4];
  float v[8]; float ss = 0.0f;
#pragma unroll
  for (int j = 0; j < 8; ++j) { v[j] = bh[b * DET + tid + 256 * j]; ss += v[j] * v[j]; }
#pragma unroll
  for (int m = 1; m < 64; m <<= 1) ss += __shfl_xor(ss, m);
  if ((tid & 63) == 0) red[tid >> 6] = ss;
  __syncthreads();
  float rm = sqrtf((red[0] + red[1] + red[2] + red[3]) / 2048.0f + 1e-8f);
#pragma unroll
  for (int j = 0; j < 8; ++j) {
    int o = tid + 256 * j;
    xn[b * DET + o] = silu_f(v[j] / rm * snh[o]);
  }
}

// gates -> new deter (f32), d_seq f32 out
__global__ __launch_bounds__(256) void updF(const float* __restrict__ gates,
    float* __restrict__ deter, float* __restrict__ dout, int t)
{
  int b = blockIdx.x, tid = threadIdx.x;
#pragma unroll
  for (int j = 0; j < 8; ++j) {
    int d = tid + j * 256;
    float gr = gates[b * 6144 + d];
    float gc = gates[b * 6144 + 2048 + d];
    float gu = gates[b * 6144 + 4096 + d];
    float r = 1.0f / (1.0f + expf(-gr));
    float cnd = tanhf(r * gc);
    float u = 1.0f / (1.0f + expf(-(gu - 1.0f)));
    float nd = u * cnd + (1.0f - u) * deter[b * DET + d];
    deter[b * DET + d] = nd;
    dout[(size_t)(b * NT + t) * DET + d] = nd;
  }
}

// q1 + softmax + unimix + gumbel argmax (f32)
__global__ __launch_bounds__(256) void q1_sampleF(
    const float* __restrict__ hq, const float* __restrict__ s_q0,
    const float* __restrict__ w_q1, const float* __restrict__ b_q1,
    float* __restrict__ stoch, float* __restrict__ out_s,
    float* __restrict__ out_post, int t)
{
  __shared__ float sh[8][512];
  __shared__ float ssr[8];
  const int tid = threadIdx.x;
  const int colbase = blockIdx.x * 128;
  const int rbase = blockIdx.y * 8;
  const int r_loc = tid >> 5, l32 = tid & 31;
  const int b = rbase + r_loc;
  {
    float ss = 0.0f;
#pragma unroll
    for (int j = 0; j < 16; ++j) {
      float v = hq[b * 512 + l32 + j * 32];
      sh[r_loc][l32 + j * 32] = v;
      ss += v * v;
    }
#pragma unroll
    for (int m = 1; m < 32; m <<= 1) ss += __shfl_xor(ss, m);
    if (l32 == 0) ssr[r_loc] = ss;
  }
  __syncthreads();
  {
    float rm = sqrtf(ssr[r_loc] / 512.0f + 1e-8f);
#pragma unroll
    for (int j = 0; j < 16; ++j) {
      int o = l32 + j * 32;
      sh[r_loc][o] = silu_f(sh[r_loc][o] / rm * s_q0[o]);
    }
  }
  __syncthreads();
  float acc[4] = {0, 0, 0, 0};
#pragma unroll 8
  for (int k = 0; k < 512; ++k) {
    float h = sh[r_loc][k];
#pragma unroll
    for (int j = 0; j < 4; ++j) acc[j] += h * w_q1[(size_t)k * 1024 + colbase + j * 32 + l32];
  }
#pragma unroll
  for (int j = 0; j < 4; ++j) {
    int col = colbase + j * 32 + l32;
    float logit = acc[j] + b_q1[col];
    out_post[(size_t)(b * NT + t) * SDIM + col] = logit;
    float m = logit;
#pragma unroll
    for (int mm = 1; mm < 32; mm <<= 1) m = fmaxf(m, __shfl_xor(m, mm));
    float e = expf(logit - m);
    float s = e;
#pragma unroll
    for (int mm = 1; mm < 32; mm <<= 1) s += __shfl_xor(s, mm);
    float p = 0.99f * (e / s) + 0.0003125f;
    float val = logf(p) + gumbel_f(t, b, col >> 5, l32);
    float bv = val; int bi = l32;
#pragma unroll
    for (int mm = 1; mm < 32; mm <<= 1) {
      float ov = __shfl_xor(bv, mm);
      int oi = __shfl_xor(bi, mm);
      if (ov > bv || (ov == bv && oi < bi)) { bv = ov; bi = oi; }
    }
    float ohv = (1.0f + p) - p;
    float oh = (bi == l32) ? ohv : 0.0f;
    stoch[b * SDIM + col] = oh;
    out_s[(size_t)(b * NT + t) * SDIM + col] = oh;
  }
}

// ---------------- f32 prior path (unchanged from R10) ----------------
template<int NACC>
__global__ __launch_bounds__(256) void gemm_k(const float* __restrict__ A, int lda,
    const float* __restrict__ W, int ldw, const float* __restrict__ bias,
    float* __restrict__ C, int ldc, int K)
{
  constexpr int RPG = 8, KT = 64, RT = RPG * NACC;
  __shared__ float As[RT][KT];
  const int tid = threadIdx.x;
  const int o = blockIdx.x * 32 + (tid & 31);
  const int rg = tid >> 5;
  const int rbase = blockIdx.y * RT;
  float acc[NACC];
#pragma unroll
  for (int j = 0; j < NACC; ++j) acc[j] = 0.0f;
  for (int k0 = 0; k0 < K; k0 += KT) {
#pragma unroll
    for (int idx = tid; idx < RT * KT; idx += 256) {
      int rr = idx / KT, kk = idx % KT;
      As[rr][kk] = A[(size_t)(rbase + rr) * lda + (size_t)(k0 + kk)];
    }
    __syncthreads();
#pragma unroll 8
    for (int kk = 0; kk < KT; ++kk) {
      float w = W[(size_t)(k0 + kk) * ldw + o];
#pragma unroll
      for (int j = 0; j < NACC; ++j) acc[j] += As[rg + j * RPG][kk] * w;
    }
    __syncthreads();
  }
  float bv = bias ? bias[o] : 0.0f;
#pragma unroll
  for (int j = 0; j < NACC; ++j) {
    int r = rbase + rg + j * RPG;
    C[(size_t)r * ldc + o] = acc[j] + bv;
  }
}

__global__ __launch_bounds__(256) void norm_h(const float* __restrict__ raw,
                                              const float* __restrict__ scale,
                                              float* __restrict__ outp)
{
  int r = blockIdx.x, tid = threadIdx.x;
  __shared__ float red[4];
  float v0 = raw[(size_t)r * 512 + tid];
  float v1 = raw[(size_t)r * 512 + 256 + tid];
  float ss = v0 * v0 + v1 * v1;
#pragma unroll
  for (int m = 1; m < 64; m <<= 1) ss += __shfl_xor(ss, m);
  if ((tid & 63) == 0) red[tid >> 6] = ss;
  __syncthreads();
  float rm = sqrtf((red[0] + red[1] + red[2] + red[3]) / 512.0f + 1e-8f);
  outp[(size_t)r * 512 + tid]       = silu_f(v0 / rm * scale[tid]);
  outp[(size_t)r * 512 + 256 + tid] = silu_f(v1 / rm * scale[256 + tid]);
}

// ---------------- launch ----------------
extern "C" void kernel_launch(void* const* d_in, const int* in_sizes, int n_in,
                              void* d_out, int out_size, void* d_ws, size_t ws_size,
                              hipStream_t stream)
{
  const float* tokens     = (const float*)d_in[0];
  const float* actions    = (const float*)d_in[1];
  const float* w_in_deter = (const float*)d_in[3];
  const float* b_in_deter = (const float*)d_in[4];
  const float* w_in_stoch = (const float*)d_in[5];
  const float* b_in_stoch = (const float*)d_in[6];
  const float* w_in_act   = (const float*)d_in[7];
  const float* b_in_act   = (const float*)d_in[8];
  const float* s_n0 = (const float*)d_in[9];
  const float* s_n1 = (const float*)d_in[10];
  const float* s_n2 = (const float*)d_in[11];
  const float* w_blk_h = (const float*)d_in[12];
  const float* b_blk_h = (const float*)d_in[13];
  const float* s_nh = (const float*)d_in[14];
  const float* w_blk_g = (const float*)d_in[15];
  const float* b_blk_g = (const float*)d_in[16];
  const float* w_p0 = (const float*)d_in[17];
  const float* b_p0 = (const float*)d_in[18];
  const float* s_p0 = (const float*)d_in[19];
  const float* w_p1 = (const float*)d_in[20];
  const float* b_p1 = (const float*)d_in[21];
  const float* s_p1 = (const float*)d_in[22];
  const float* w_p2 = (const float*)d_in[23];
  const float* b_p2 = (const float*)d_in[24];
  const float* w_q0 = (const float*)d_in[25];
  const float* b_q0 = (const float*)d_in[26];
  const float* s_q0 = (const float*)d_in[27];
  const float* w_q1 = (const float*)d_in[28];
  const float* b_q1 = (const float*)d_in[29];

  // f32 working set (4.34 MB), prior ping-pong overlays it after the loop (16.78 MB total)
  float* ws = (float*)d_ws;
  float* deter = ws;                  // 131072
  float* stoch = deter + 131072;      // 65536
  float* act   = stoch + 65536;       // 4096
  float* t0b   = act + 4096;          // 32768
  float* t1b   = t0b + 32768;         // 32768
  float* t2b   = t1b + 32768;         // 32768
  float* comb  = t2b + 32768;         // 98304
  float* bh    = comb + 98304;        // 131072
  float* xn    = bh + 131072;         // 131072
  float* gates = xn + 131072;         // 393216
  float* hq    = gates + 393216;      // 32768   -> 1,085,440 floats total
  float* hp_a  = ws;                  // reuse (state dead after loop), 2097152
  float* hp_b  = ws + 2097152;        // 2097152  -> high-water 16.78 MB (< R10's 17.07)

  float* outf = (float*)d_out;
  float* out_d    = outf;
  float* out_s    = outf + OS;
  float* out_pri  = outf + OPRI;
  float* out_post = outf + OPOST;

  zero_initF<<<dim3(256), dim3(256), 0, stream>>>(deter, stoch);

  for (int t = 0; t < NT; ++t) {
    prepF<<<dim3(NB), dim3(256), 0, stream>>>(actions, t, deter, stoch, act);
    GDf g0{deter, w_in_deter, b_in_deter, t0b, DET, DET};
    GDf g1{stoch, w_in_stoch, b_in_stoch, t1b, SDIM, SDIM};
    GDf g2{act, w_in_act, b_in_act, t2b, ACTD, ACTD};
    gemm_x3F<<<dim3(16, 4, 3), dim3(256), 0, stream>>>(g0, g1, g2);
    norm_combF<<<dim3(NB), dim3(256), 0, stream>>>(t0b, t1b, t2b, s_n0, s_n1, s_n2, comb);
    gemm_bhF<<<dim3(8, 16), dim3(256), 0, stream>>>(deter, comb, w_blk_h, b_blk_h, bh);
    norm_xnF<<<dim3(NB), dim3(256), 0, stream>>>(bh, s_nh, xn);
    gemm_bgF<<<dim3(24, 16), dim3(256), 0, stream>>>(xn, w_blk_g, b_blk_g, gates);
    updF<<<dim3(NB), dim3(256), 0, stream>>>(gates, deter, out_d, t);
    gemm_q0F<<<dim3(16, 4), dim3(256), 0, stream>>>(deter, tokens, w_q0, b_q0, hq, t);
    q1_sampleF<<<dim3(8, 8), dim3(256), 0, stream>>>(hq, s_q0, w_q1, b_q1,
        stoch, out_s, out_post, t);
  }

  // batched f32 prior from d_seq
  gemm_k<4><<<dim3(16, 128), dim3(256), 0, stream>>>(
      out_d, DET, w_p0, 512, b_p0, hp_a, 512, DET);
  norm_h<<<dim3(NB * NT), dim3(256), 0, stream>>>(hp_a, s_p0, hp_b);
  gemm_k<4><<<dim3(16, 128), dim3(256), 0, stream>>>(
      hp_b, 512, w_p1, 512, b_p1, hp_a, 512, 512);
  norm_h<<<dim3(NB * NT), dim3(256), 0, stream>>>(hp_a, s_p1, hp_b);
  gemm_k<4><<<dim3(32, 128), dim3(256), 0, stream>>>(
      hp_b, 512, w_p2, 1024, b_p2, out_pri, 1024, 512);
}

// Round 17
// 25430.266 us; speedup vs baseline: 1.7556x; 1.2211x over previous
//
#include <hip/hip_runtime.h>
#include <hip/hip_bf16.h>

// ROUND 17 = R16 (passing, 31ms) with occupancy-boosted grids: NACC 4->1 / acc2->1 on the
// SAME proven kernels. Per-output K-chains unchanged => bit-identical results to R16.

// ---------------- constants ----------------
constexpr int NB = 64;
constexpr int NT = 64;
constexpr int DET = 2048;
constexpr int SDIM = 1024;
constexpr int ACTD = 64;
constexpr int DPER = 256;
constexpr int COREIN = 1792;

constexpr size_t OS   = (size_t)NB * NT * DET;
constexpr size_t OPRI = OS + (size_t)NB * NT * SDIM;
constexpr size_t OPOST= OPRI + (size_t)NB * NT * SDIM;

__device__ __forceinline__ float silu_f(float v) { return v / (1.0f + expf(-v)); }
__device__ __forceinline__ unsigned rotl32(unsigned x, int r) { return (x << r) | (x >> (32 - r)); }

// ---------------- JAX threefry2x32 gumbel, key(42), partitionable XOR (verified R10) -------
__device__ float gumbel_f(int t, int b, int s, int c) {
  unsigned idx = ((unsigned)(t * NB + b) * 32u + (unsigned)s) * 32u + (unsigned)c;
  unsigned x0 = 0u, x1 = idx;
  const unsigned k0 = 0u, k1 = 42u, k2 = 0x1BD11BDAu ^ k0 ^ k1;
  x0 += k0; x1 += k1;
#define TFR(r) { x0 += x1; x1 = rotl32(x1, r); x1 ^= x0; }
  TFR(13) TFR(15) TFR(26) TFR(6)  x0 += k1; x1 += k2 + 1u;
  TFR(17) TFR(29) TFR(16) TFR(24) x0 += k2; x1 += k0 + 2u;
  TFR(13) TFR(15) TFR(26) TFR(6)  x0 += k0; x1 += k1 + 3u;
  TFR(17) TFR(29) TFR(16) TFR(24) x0 += k1; x1 += k2 + 4u;
  TFR(13) TFR(15) TFR(26) TFR(6)  x0 += k2; x1 += k0 + 5u;
#undef TFR
  unsigned bits = x0 ^ x1;
  float f = __uint_as_float((bits >> 9) | 0x3f800000u) - 1.0f;
  const float TINY = 1.17549435e-38f;
  float u = fmaxf(TINY, f + TINY);
  double g = -log(-log((double)u));
  return (float)g;
}

// ---------------- f32 GEMM (R16 body, generic NACC) ----------------
template<int NACC>
__device__ __forceinline__ void gemm_bodyF(const float* __restrict__ A, int lda,
    const float* __restrict__ W, int ldw, const float* __restrict__ bias,
    float* __restrict__ C, int ldc, int K)
{
  constexpr int RPG = 8, KT = 64, RT = RPG * NACC;
  __shared__ float As[RT][KT];
  const int tid = threadIdx.x;
  const int o = blockIdx.x * 32 + (tid & 31);
  const int rg = tid >> 5;
  const int rbase = blockIdx.y * RT;
  float acc[NACC];
#pragma unroll
  for (int j = 0; j < NACC; ++j) acc[j] = 0.0f;
  for (int k0 = 0; k0 < K; k0 += KT) {
#pragma unroll
    for (int idx = tid; idx < RT * KT; idx += 256) {
      int rr = idx / KT, kk = idx % KT;
      As[rr][kk] = A[(size_t)(rbase + rr) * lda + (size_t)(k0 + kk)];
    }
    __syncthreads();
#pragma unroll 8
    for (int kk = 0; kk < KT; ++kk) {
      float w = W[(size_t)(k0 + kk) * ldw + o];
#pragma unroll
      for (int j = 0; j < NACC; ++j) acc[j] += As[rg + j * RPG][kk] * w;
    }
    __syncthreads();
  }
  float bv = bias ? bias[o] : 0.0f;
#pragma unroll
  for (int j = 0; j < NACC; ++j) {
    int r = rbase + rg + j * RPG;
    C[(size_t)r * ldc + o] = acc[j] + bv;
  }
}

struct GDf { const float* A; const float* W; const float* bias; float* C; int lda; int K; };
__global__ __launch_bounds__(256) void gemm_x3F(GDf a, GDf b, GDf c) {
  GDf d = (blockIdx.z == 0) ? a : (blockIdx.z == 1) ? b : c;
  gemm_bodyF<1>(d.A, d.lda, d.W, 512, d.bias, d.C, 512, d.K);   // grid.y = 8
}

// ---------------- q0 (acc1, RT=8): grid (16, 8) ----------------
__global__ __launch_bounds__(256) void gemm_q0F(
    const float* __restrict__ deter, const float* __restrict__ tokens,
    const float* __restrict__ w_q0, const float* __restrict__ b_q0,
    float* __restrict__ hq, int t)
{
  constexpr int KT = 64, RT = 8;
  __shared__ float As[RT][KT];
  const int tid = threadIdx.x;
  const int o = blockIdx.x * 32 + (tid & 31);
  const int rg = tid >> 5;
  const int rbase = blockIdx.y * RT;
  float acc = 0.0f;
  for (int k0 = 0; k0 < DET + 512; k0 += KT) {
#pragma unroll
    for (int idx = tid; idx < RT * KT; idx += 256) {
      int rr = idx / KT, kk = idx % KT;
      int g = k0 + kk, b = rbase + rr;
      As[rr][kk] = (g < DET) ? deter[b * DET + g]
                             : tokens[((size_t)(b * NT + t)) * 512 + (g - DET)];
    }
    __syncthreads();
#pragma unroll 8
    for (int kk = 0; kk < KT; ++kk) {
      float w = w_q0[(size_t)(k0 + kk) * 512 + o];
      acc += As[rg][kk] * w;
    }
    __syncthreads();
  }
  hq[(rbase + rg) * 512 + o] = acc + b_q0[o];
}

// ---------------- block_h (generic NACC; NACC=1 -> grid (8, 64)) ----------------
template<int NACC>
__global__ __launch_bounds__(256) void gemm_bhF(
    const float* __restrict__ deter, const float* __restrict__ comb,
    const float* __restrict__ Wh, const float* __restrict__ bh_bias,
    float* __restrict__ bh)
{
  constexpr int KT = 64, RT = 8 * NACC;
  __shared__ float As[RT][KT];
  const int tid = threadIdx.x;
  const int o = blockIdx.x * 32 + (tid & 31);
  const int rg = tid >> 5;
  const int rbase = blockIdx.y * RT;   // row = k*64 + b
  const int k = rbase >> 6;            // uniform per block (RT divides 64)
  const float* W = Wh + (size_t)k * COREIN * DPER;
  float acc[NACC];
#pragma unroll
  for (int j = 0; j < NACC; ++j) acc[j] = 0.0f;
  for (int k0 = 0; k0 < COREIN; k0 += KT) {
#pragma unroll
    for (int idx = tid; idx < RT * KT; idx += 256) {
      int rr = idx / KT, kk = idx % KT;
      int b = (rbase + rr) & 63;
      int i = k0 + kk;
      As[rr][kk] = (i < DPER) ? deter[b * DET + k * DPER + i] : comb[b * 1536 + (i - DPER)];
    }
    __syncthreads();
#pragma unroll 8
    for (int kk = 0; kk < KT; ++kk) {
      float w = W[(size_t)(k0 + kk) * DPER + o];
#pragma unroll
      for (int j = 0; j < NACC; ++j) acc[j] += As[rg + j * 8][kk] * w;
    }
    __syncthreads();
  }
  float bv = bh_bias[k * DPER + o];
#pragma unroll
  for (int j = 0; j < NACC; ++j) {
    int b = (rbase + rg + j * 8) & 63;
    bh[b * DET + k * DPER + o] = acc[j] + bv;
  }
}

// ---------------- block_g (generic NACC; NACC=1 -> grid (24, 64)) ----------------
template<int NACC>
__global__ __launch_bounds__(256) void gemm_bgF(
    const float* __restrict__ xn, const float* __restrict__ Wg,
    const float* __restrict__ bg_bias, float* __restrict__ gates)
{
  constexpr int KT = 64, RT = 8 * NACC;
  __shared__ float As[RT][KT];
  const int tid = threadIdx.x;
  const int o = blockIdx.x * 32 + (tid & 31);   // 0..767
  const int rg = tid >> 5;
  const int rbase = blockIdx.y * RT;
  const int k = rbase >> 6;
  const float* W = Wg + (size_t)k * DPER * 768;
  float acc[NACC];
#pragma unroll
  for (int j = 0; j < NACC; ++j) acc[j] = 0.0f;
  for (int k0 = 0; k0 < DPER; k0 += KT) {
#pragma unroll
    for (int idx = tid; idx < RT * KT; idx += 256) {
      int rr = idx / KT, kk = idx % KT;
      int b = (rbase + rr) & 63;
      As[rr][kk] = xn[b * DET + k * DPER + k0 + kk];
    }
    __syncthreads();
#pragma unroll 8
    for (int kk = 0; kk < KT; ++kk) {
      float w = W[(size_t)(k0 + kk) * 768 + o];
#pragma unroll
      for (int j = 0; j < NACC; ++j) acc[j] += As[rg + j * 8][kk] * w;
    }
    __syncthreads();
  }
  float bv = bg_bias[k * 768 + o];
#pragma unroll
  for (int j = 0; j < NACC; ++j) {
    int b = (rbase + rg + j * 8) & 63;
    gates[b * 6144 + k * 768 + o] = acc[j] + bv;
  }
}

// ---------------- small kernels (unchanged from R16) ----------------
__global__ void zero_initF(float* deter, float* stoch) {
  int i = blockIdx.x * 256 + threadIdx.x;
  for (int idx = i; idx < NB * DET; idx += gridDim.x * 256) deter[idx] = 0.0f;
  for (int idx = i; idx < NB * SDIM; idx += gridDim.x * 256) stoch[idx] = 0.0f;
}

__global__ void prepF(const float* __restrict__ actions,
                      int t, float* deter, float* stoch, float* act_buf) {
  int b = blockIdx.x, tid = threadIdx.x;
  bool first = (t == 0);
  if (first) {
    for (int i = tid; i < DET; i += 256) deter[b * DET + i] = 0.0f;
    for (int i = tid; i < SDIM; i += 256) stoch[b * SDIM + i] = 0.0f;
  }
  if (tid < ACTD) {
    float a = first ? 0.0f : actions[(size_t)(b * NT + t) * ACTD + tid];
    act_buf[b * ACTD + tid] = a / fmaxf(fabsf(a), 1.0f);
  }
}

__global__ __launch_bounds__(256) void norm_combF(
    const float* __restrict__ t0, const float* __restrict__ t1, const float* __restrict__ t2,
    const float* __restrict__ s0, const float* __restrict__ s1, const float* __restrict__ s2,
    float* __restrict__ comb)
{
  int b = blockIdx.x, tid = threadIdx.x;
  __shared__ float red[4];
  for (int part = 0; part < 3; ++part) {
    const float* src = part == 0 ? t0 : part == 1 ? t1 : t2;
    const float* sc  = part == 0 ? s0 : part == 1 ? s1 : s2;
    float v0 = src[b * 512 + tid];
    float v1 = src[b * 512 + 256 + tid];
    float ss = v0 * v0 + v1 * v1;
#pragma unroll
    for (int m = 1; m < 64; m <<= 1) ss += __shfl_xor(ss, m);
    if ((tid & 63) == 0) red[tid >> 6] = ss;
    __syncthreads();
    float rm = sqrtf((red[0] + red[1] + red[2] + red[3]) / 512.0f + 1e-8f);
    comb[b * 1536 + part * 512 + tid]       = silu_f(v0 / rm * sc[tid]);
    comb[b * 1536 + part * 512 + 256 + tid] = silu_f(v1 / rm * sc[256 + tid]);
    __syncthreads();
  }
}

__global__ __launch_bounds__(256) void norm_xnF(const float* __restrict__ bh,
                                                const float* __restrict__ snh,
                                                float* __restrict__ xn)
{
  int b = blockIdx.x, tid = threadIdx.x;
  __shared__ float red[4];
  float v[8]; float ss = 0.0f;
#pragma unroll
  for (int j = 0; j < 8; ++j) { v[j] = bh[b * DET + tid + 256 * j]; ss += v[j] * v[j]; }
#pragma unroll
  for (int m = 1; m < 64; m <<= 1) ss += __shfl_xor(ss, m);
  if ((tid & 63) == 0) red[tid >> 6] = ss;
  __syncthreads();
  float rm = sqrtf((red[0] + red[1] + red[2] + red[3]) / 2048.0f + 1e-8f);
#pragma unroll
  for (int j = 0; j < 8; ++j) {
    int o = tid + 256 * j;
    xn[b * DET + o] = silu_f(v[j] / rm * snh[o]);
  }
}

__global__ __launch_bounds__(256) void updF(const float* __restrict__ gates,
    float* __restrict__ deter, float* __restrict__ dout, int t)
{
  int b = blockIdx.x, tid = threadIdx.x;
#pragma unroll
  for (int j = 0; j < 8; ++j) {
    int d = tid + j * 256;
    float gr = gates[b * 6144 + d];
    float gc = gates[b * 6144 + 2048 + d];
    float gu = gates[b * 6144 + 4096 + d];
    float r = 1.0f / (1.0f + expf(-gr));
    float cnd = tanhf(r * gc);
    float u = 1.0f / (1.0f + expf(-(gu - 1.0f)));
    float nd = u * cnd + (1.0f - u) * deter[b * DET + d];
    deter[b * DET + d] = nd;
    dout[(size_t)(b * NT + t) * DET + d] = nd;
  }
}

__global__ __launch_bounds__(256) void q1_sampleF(
    const float* __restrict__ hq, const float* __restrict__ s_q0,
    const float* __restrict__ w_q1, const float* __restrict__ b_q1,
    float* __restrict__ stoch, float* __restrict__ out_s,
    float* __restrict__ out_post, int t)
{
  __shared__ float sh[8][512];
  __shared__ float ssr[8];
  const int tid = threadIdx.x;
  const int colbase = blockIdx.x * 128;
  const int rbase = blockIdx.y * 8;
  const int r_loc = tid >> 5, l32 = tid & 31;
  const int b = rbase + r_loc;
  {
    float ss = 0.0f;
#pragma unroll
    for (int j = 0; j < 16; ++j) {
      float v = hq[b * 512 + l32 + j * 32];
      sh[r_loc][l32 + j * 32] = v;
      ss += v * v;
    }
#pragma unroll
    for (int m = 1; m < 32; m <<= 1) ss += __shfl_xor(ss, m);
    if (l32 == 0) ssr[r_loc] = ss;
  }
  __syncthreads();
  {
    float rm = sqrtf(ssr[r_loc] / 512.0f + 1e-8f);
#pragma unroll
    for (int j = 0; j < 16; ++j) {
      int o = l32 + j * 32;
      sh[r_loc][o] = silu_f(sh[r_loc][o] / rm * s_q0[o]);
    }
  }
  __syncthreads();
  float acc[4] = {0, 0, 0, 0};
#pragma unroll 8
  for (int k = 0; k < 512; ++k) {
    float h = sh[r_loc][k];
#pragma unroll
    for (int j = 0; j < 4; ++j) acc[j] += h * w_q1[(size_t)k * 1024 + colbase + j * 32 + l32];
  }
#pragma unroll
  for (int j = 0; j < 4; ++j) {
    int col = colbase + j * 32 + l32;
    float logit = acc[j] + b_q1[col];
    out_post[(size_t)(b * NT + t) * SDIM + col] = logit;
    float m = logit;
#pragma unroll
    for (int mm = 1; mm < 32; mm <<= 1) m = fmaxf(m, __shfl_xor(m, mm));
    float e = expf(logit - m);
    float s = e;
#pragma unroll
    for (int mm = 1; mm < 32; mm <<= 1) s += __shfl_xor(s, mm);
    float p = 0.99f * (e / s) + 0.0003125f;
    float val = logf(p) + gumbel_f(t, b, col >> 5, l32);
    float bv = val; int bi = l32;
#pragma unroll
    for (int mm = 1; mm < 32; mm <<= 1) {
      float ov = __shfl_xor(bv, mm);
      int oi = __shfl_xor(bi, mm);
      if (ov > bv || (ov == bv && oi < bi)) { bv = ov; bi = oi; }
    }
    float ohv = (1.0f + p) - p;
    float oh = (bi == l32) ? ohv : 0.0f;
    stoch[b * SDIM + col] = oh;
    out_s[(size_t)(b * NT + t) * SDIM + col] = oh;
  }
}

// ---------------- f32 prior path (unchanged) ----------------
template<int NACC>
__global__ __launch_bounds__(256) void gemm_k(const float* __restrict__ A, int lda,
    const float* __restrict__ W, int ldw, const float* __restrict__ bias,
    float* __restrict__ C, int ldc, int K)
{
  constexpr int RPG = 8, KT = 64, RT = RPG * NACC;
  __shared__ float As[RT][KT];
  const int tid = threadIdx.x;
  const int o = blockIdx.x * 32 + (tid & 31);
  const int rg = tid >> 5;
  const int rbase = blockIdx.y * RT;
  float acc[NACC];
#pragma unroll
  for (int j = 0; j < NACC; ++j) acc[j] = 0.0f;
  for (int k0 = 0; k0 < K; k0 += KT) {
#pragma unroll
    for (int idx = tid; idx < RT * KT; idx += 256) {
      int rr = idx / KT, kk = idx % KT;
      As[rr][kk] = A[(size_t)(rbase + rr) * lda + (size_t)(k0 + kk)];
    }
    __syncthreads();
#pragma unroll 8
    for (int kk = 0; kk < KT; ++kk) {
      float w = W[(size_t)(k0 + kk) * ldw + o];
#pragma unroll
      for (int j = 0; j < NACC; ++j) acc[j] += As[rg + j * RPG][kk] * w;
    }
    __syncthreads();
  }
  float bv = bias ? bias[o] : 0.0f;
#pragma unroll
  for (int j = 0; j < NACC; ++j) {
    int r = rbase + rg + j * RPG;
    C[(size_t)r * ldc + o] = acc[j] + bv;
  }
}

__global__ __launch_bounds__(256) void norm_h(const float* __restrict__ raw,
                                              const float* __restrict__ scale,
                                              float* __restrict__ outp)
{
  int r = blockIdx.x, tid = threadIdx.x;
  __shared__ float red[4];
  float v0 = raw[(size_t)r * 512 + tid];
  float v1 = raw[(size_t)r * 512 + 256 + tid];
  float ss = v0 * v0 + v1 * v1;
#pragma unroll
  for (int m = 1; m < 64; m <<= 1) ss += __shfl_xor(ss, m);
  if ((tid & 63) == 0) red[tid >> 6] = ss;
  __syncthreads();
  float rm = sqrtf((red[0] + red[1] + red[2] + red[3]) / 512.0f + 1e-8f);
  outp[(size_t)r * 512 + tid]       = silu_f(v0 / rm * scale[tid]);
  outp[(size_t)r * 512 + 256 + tid] = silu_f(v1 / rm * scale[256 + tid]);
}

// ---------------- launch ----------------
extern "C" void kernel_launch(void* const* d_in, const int* in_sizes, int n_in,
                              void* d_out, int out_size, void* d_ws, size_t ws_size,
                              hipStream_t stream)
{
  const float* tokens     = (const float*)d_in[0];
  const float* actions    = (const float*)d_in[1];
  const float* w_in_deter = (const float*)d_in[3];
  const float* b_in_deter = (const float*)d_in[4];
  const float* w_in_stoch = (const float*)d_in[5];
  const float* b_in_stoch = (const float*)d_in[6];
  const float* w_in_act   = (const float*)d_in[7];
  const float* b_in_act   = (const float*)d_in[8];
  const float* s_n0 = (const float*)d_in[9];
  const float* s_n1 = (const float*)d_in[10];
  const float* s_n2 = (const float*)d_in[11];
  const float* w_blk_h = (const float*)d_in[12];
  const float* b_blk_h = (const float*)d_in[13];
  const float* s_nh = (const float*)d_in[14];
  const float* w_blk_g = (const float*)d_in[15];
  const float* b_blk_g = (const float*)d_in[16];
  const float* w_p0 = (const float*)d_in[17];
  const float* b_p0 = (const float*)d_in[18];
  const float* s_p0 = (const float*)d_in[19];
  const float* w_p1 = (const float*)d_in[20];
  const float* b_p1 = (const float*)d_in[21];
  const float* s_p1 = (const float*)d_in[22];
  const float* w_p2 = (const float*)d_in[23];
  const float* b_p2 = (const float*)d_in[24];
  const float* w_q0 = (const float*)d_in[25];
  const float* b_q0 = (const float*)d_in[26];
  const float* s_q0 = (const float*)d_in[27];
  const float* w_q1 = (const float*)d_in[28];
  const float* b_q1 = (const float*)d_in[29];

  float* ws = (float*)d_ws;
  float* deter = ws;                  // 131072
  float* stoch = deter + 131072;      // 65536
  float* act   = stoch + 65536;       // 4096
  float* t0b   = act + 4096;          // 32768
  float* t1b   = t0b + 32768;         // 32768
  float* t2b   = t1b + 32768;         // 32768
  float* comb  = t2b + 32768;         // 98304
  float* bh    = comb + 98304;        // 131072
  float* xn    = bh + 131072;         // 131072
  float* gates = xn + 131072;         // 393216
  float* hq    = gates + 393216;      // 32768
  float* hp_a  = ws;                  // prior overlay (loop state dead)
  float* hp_b  = ws + 2097152;        // high-water 16.78 MB (proven available)

  float* outf = (float*)d_out;
  float* out_d    = outf;
  float* out_s    = outf + OS;
  float* out_pri  = outf + OPRI;
  float* out_post = outf + OPOST;

  zero_initF<<<dim3(256), dim3(256), 0, stream>>>(deter, stoch);

  for (int t = 0; t < NT; ++t) {
    prepF<<<dim3(NB), dim3(256), 0, stream>>>(actions, t, deter, stoch, act);
    GDf g0{deter, w_in_deter, b_in_deter, t0b, DET, DET};
    GDf g1{stoch, w_in_stoch, b_in_stoch, t1b, SDIM, SDIM};
    GDf g2{act, w_in_act, b_in_act, t2b, ACTD, ACTD};
    gemm_x3F<<<dim3(16, 8, 3), dim3(256), 0, stream>>>(g0, g1, g2);
    norm_combF<<<dim3(NB), dim3(256), 0, stream>>>(t0b, t1b, t2b, s_n0, s_n1, s_n2, comb);
    gemm_bhF<1><<<dim3(8, 64), dim3(256), 0, stream>>>(deter, comb, w_blk_h, b_blk_h, bh);
    norm_xnF<<<dim3(NB), dim3(256), 0, stream>>>(bh, s_nh, xn);
    gemm_bgF<1><<<dim3(24, 64), dim3(256), 0, stream>>>(xn, w_blk_g, b_blk_g, gates);
    updF<<<dim3(NB), dim3(256), 0, stream>>>(gates, deter, out_d, t);
    gemm_q0F<<<dim3(16, 8), dim3(256), 0, stream>>>(deter, tokens, w_q0, b_q0, hq, t);
    q1_sampleF<<<dim3(8, 8), dim3(256), 0, stream>>>(hq, s_q0, w_q1, b_q1,
        stoch, out_s, out_post, t);
  }

  // batched f32 prior from d_seq
  gemm_k<4><<<dim3(16, 128), dim3(256), 0, stream>>>(
      out_d, DET, w_p0, 512, b_p0, hp_a, 512, DET);
  norm_h<<<dim3(NB * NT), dim3(256), 0, stream>>>(hp_a, s_p0, hp_b);
  gemm_k<4><<<dim3(16, 128), dim3(256), 0, stream>>>(
      hp_b, 512, w_p1, 512, b_p1, hp_a, 512, 512);
  norm_h<<<dim3(NB * NT), dim3(256), 0, stream>>>(hp_a, s_p1, hp_b);
  gemm_k<4><<<dim3(32, 128), dim3(256), 0, stream>>>(
      hp_b, 512, w_p2, 1024, b_p2, out_pri, 1024, 512);
}

// Round 18
// 19680.632 us; speedup vs baseline: 2.2685x; 1.2921x over previous
//
#include <hip/hip_runtime.h>
#include <hip/hip_bf16.h>

// ROUND 18 = R17 (passing, 25.4ms) + W-tile LDS staging in all GEMMs (bit-identical chains)
//            + prep launch eliminated (act-norm folded into x3; t=0 zeroing via zero_init).

// ---------------- constants ----------------
constexpr int NB = 64;
constexpr int NT = 64;
constexpr int DET = 2048;
constexpr int SDIM = 1024;
constexpr int ACTD = 64;
constexpr int DPER = 256;
constexpr int COREIN = 1792;

constexpr size_t OS   = (size_t)NB * NT * DET;
constexpr size_t OPRI = OS + (size_t)NB * NT * SDIM;
constexpr size_t OPOST= OPRI + (size_t)NB * NT * SDIM;

__device__ __forceinline__ float silu_f(float v) { return v / (1.0f + expf(-v)); }
__device__ __forceinline__ unsigned rotl32(unsigned x, int r) { return (x << r) | (x >> (32 - r)); }

// ---------------- JAX threefry2x32 gumbel, key(42), partitionable XOR (verified R10) -------
__device__ float gumbel_f(int t, int b, int s, int c) {
  unsigned idx = ((unsigned)(t * NB + b) * 32u + (unsigned)s) * 32u + (unsigned)c;
  unsigned x0 = 0u, x1 = idx;
  const unsigned k0 = 0u, k1 = 42u, k2 = 0x1BD11BDAu ^ k0 ^ k1;
  x0 += k0; x1 += k1;
#define TFR(r) { x0 += x1; x1 = rotl32(x1, r); x1 ^= x0; }
  TFR(13) TFR(15) TFR(26) TFR(6)  x0 += k1; x1 += k2 + 1u;
  TFR(17) TFR(29) TFR(16) TFR(24) x0 += k2; x1 += k0 + 2u;
  TFR(13) TFR(15) TFR(26) TFR(6)  x0 += k0; x1 += k1 + 3u;
  TFR(17) TFR(29) TFR(16) TFR(24) x0 += k1; x1 += k2 + 4u;
  TFR(13) TFR(15) TFR(26) TFR(6)  x0 += k2; x1 += k0 + 5u;
#undef TFR
  unsigned bits = x0 ^ x1;
  float f = __uint_as_float((bits >> 9) | 0x3f800000u) - 1.0f;
  const float TINY = 1.17549435e-38f;
  float u = fmaxf(TINY, f + TINY);
  double g = -log(-log((double)u));
  return (float)g;
}

// ---------------- f32 GEMM with A- and W-tile LDS staging ----------------
// Same thread->output map and K-chain order as R17 (bit-identical results).
template<int NACC>
__device__ __forceinline__ void gemm_bodyS(const float* __restrict__ A, int lda,
    const float* __restrict__ W, int ldw, const float* __restrict__ bias,
    float* __restrict__ C, int ldc, int K)
{
  constexpr int RPG = 8, KT = 64, RT = RPG * NACC;
  __shared__ float As[RT][KT];
  __shared__ float Ws[KT][32];
  const int tid = threadIdx.x;
  const int lane = tid & 31;
  const int colbase = blockIdx.x * 32;
  const int o = colbase + lane;
  const int rg = tid >> 5;
  const int rbase = blockIdx.y * RT;
  float acc[NACC];
#pragma unroll
  for (int j = 0; j < NACC; ++j) acc[j] = 0.0f;
  for (int k0 = 0; k0 < K; k0 += KT) {
#pragma unroll
    for (int idx = tid; idx < RT * KT; idx += 256) {
      int rr = idx / KT, kk = idx % KT;
      As[rr][kk] = A[(size_t)(rbase + rr) * lda + (size_t)(k0 + kk)];
    }
#pragma unroll
    for (int idx = tid; idx < KT * 32; idx += 256) {
      int kk = idx >> 5, c = idx & 31;
      Ws[kk][c] = W[(size_t)(k0 + kk) * ldw + colbase + c];
    }
    __syncthreads();
#pragma unroll 8
    for (int kk = 0; kk < KT; ++kk) {
      float w = Ws[kk][lane];
#pragma unroll
      for (int j = 0; j < NACC; ++j) acc[j] += As[rg + j * RPG][kk] * w;
    }
    __syncthreads();
  }
  float bv = bias ? bias[o] : 0.0f;
#pragma unroll
  for (int j = 0; j < NACC; ++j) {
    int r = rbase + rg + j * RPG;
    C[(size_t)r * ldc + o] = acc[j] + bv;
  }
}

// x3: z selects {deter@w_d, stoch@w_s, actions(norm)@w_a}; act-norm folded (prep eliminated)
struct GDf { const float* A; const float* W; const float* bias; float* C; int lda; int K; int isact; };
__global__ __launch_bounds__(256) void gemm_x3F(GDf a, GDf b, GDf c, int t) {
  GDf d = (blockIdx.z == 0) ? a : (blockIdx.z == 1) ? b : c;
  if (!d.isact) {
    gemm_bodyS<1>(d.A, d.lda, d.W, 512, d.bias, d.C, 512, d.K);
    return;
  }
  // actions path: K=64, A[rr][kk] = norm(actions[(row*NT+t)*64+kk]) (0 at t==0)
  constexpr int KT = 64, RT = 8;
  __shared__ float As[RT][KT];
  __shared__ float Ws[KT][32];
  const int tid = threadIdx.x;
  const int lane = tid & 31;
  const int colbase = blockIdx.x * 32;
  const int rg = tid >> 5;
  const int rbase = blockIdx.y * RT;
  const float* acts = d.A;   // raw actions [64][NT][64]
#pragma unroll
  for (int idx = tid; idx < RT * KT; idx += 256) {
    int rr = idx / KT, kk = idx % KT;
    float a = (t > 0) ? acts[((size_t)(rbase + rr) * NT + t) * ACTD + kk] : 0.0f;
    As[rr][kk] = a / fmaxf(fabsf(a), 1.0f);
  }
#pragma unroll
  for (int idx = tid; idx < KT * 32; idx += 256) {
    int kk = idx >> 5, c = idx & 31;
    Ws[kk][c] = d.W[(size_t)kk * 512 + colbase + c];
  }
  __syncthreads();
  float acc = 0.0f;
#pragma unroll 8
  for (int kk = 0; kk < KT; ++kk) acc += As[rg][kk] * Ws[kk][lane];
  d.C[(size_t)(rbase + rg) * 512 + colbase + lane] = acc + d.bias[colbase + lane];
}

// ---------------- q0 (staged): grid (16, 8), RT=8 ----------------
__global__ __launch_bounds__(256) void gemm_q0F(
    const float* __restrict__ deter, const float* __restrict__ tokens,
    const float* __restrict__ w_q0, const float* __restrict__ b_q0,
    float* __restrict__ hq, int t)
{
  constexpr int KT = 64, RT = 8;
  __shared__ float As[RT][KT];
  __shared__ float Ws[KT][32];
  const int tid = threadIdx.x;
  const int lane = tid & 31;
  const int colbase = blockIdx.x * 32;
  const int rg = tid >> 5;
  const int rbase = blockIdx.y * RT;
  float acc = 0.0f;
  for (int k0 = 0; k0 < DET + 512; k0 += KT) {
#pragma unroll
    for (int idx = tid; idx < RT * KT; idx += 256) {
      int rr = idx / KT, kk = idx % KT;
      int g = k0 + kk, b = rbase + rr;
      As[rr][kk] = (g < DET) ? deter[b * DET + g]
                             : tokens[((size_t)(b * NT + t)) * 512 + (g - DET)];
    }
#pragma unroll
    for (int idx = tid; idx < KT * 32; idx += 256) {
      int kk = idx >> 5, c = idx & 31;
      Ws[kk][c] = w_q0[(size_t)(k0 + kk) * 512 + colbase + c];
    }
    __syncthreads();
#pragma unroll 8
    for (int kk = 0; kk < KT; ++kk) acc += As[rg][kk] * Ws[kk][lane];
    __syncthreads();
  }
  hq[(rbase + rg) * 512 + colbase + lane] = acc + b_q0[colbase + lane];
}

// ---------------- block_h (staged): grid (8, 64), RT=8 ----------------
__global__ __launch_bounds__(256) void gemm_bhF(
    const float* __restrict__ deter, const float* __restrict__ comb,
    const float* __restrict__ Wh, const float* __restrict__ bh_bias,
    float* __restrict__ bh)
{
  constexpr int KT = 64, RT = 8;
  __shared__ float As[RT][KT];
  __shared__ float Ws[KT][32];
  const int tid = threadIdx.x;
  const int lane = tid & 31;
  const int colbase = blockIdx.x * 32;    // within DPER
  const int rg = tid >> 5;
  const int rbase = blockIdx.y * RT;      // row = k*64 + b
  const int k = rbase >> 6;
  const float* W = Wh + (size_t)k * COREIN * DPER;
  float acc = 0.0f;
  for (int k0 = 0; k0 < COREIN; k0 += KT) {
#pragma unroll
    for (int idx = tid; idx < RT * KT; idx += 256) {
      int rr = idx / KT, kk = idx % KT;
      int b = (rbase + rr) & 63;
      int i = k0 + kk;
      As[rr][kk] = (i < DPER) ? deter[b * DET + k * DPER + i] : comb[b * 1536 + (i - DPER)];
    }
#pragma unroll
    for (int idx = tid; idx < KT * 32; idx += 256) {
      int kk = idx >> 5, c = idx & 31;
      Ws[kk][c] = W[(size_t)(k0 + kk) * DPER + colbase + c];
    }
    __syncthreads();
#pragma unroll 8
    for (int kk = 0; kk < KT; ++kk) acc += As[rg][kk] * Ws[kk][lane];
    __syncthreads();
  }
  int b = (rbase + rg) & 63;
  bh[b * DET + k * DPER + colbase + lane] = acc + bh_bias[k * DPER + colbase + lane];
}

// ---------------- block_g (staged): grid (24, 64), RT=8 ----------------
__global__ __launch_bounds__(256) void gemm_bgF(
    const float* __restrict__ xn, const float* __restrict__ Wg,
    const float* __restrict__ bg_bias, float* __restrict__ gates)
{
  constexpr int KT = 64, RT = 8;
  __shared__ float As[RT][KT];
  __shared__ float Ws[KT][32];
  const int tid = threadIdx.x;
  const int lane = tid & 31;
  const int colbase = blockIdx.x * 32;    // 0..767 range
  const int rg = tid >> 5;
  const int rbase = blockIdx.y * RT;
  const int k = rbase >> 6;
  const float* W = Wg + (size_t)k * DPER * 768;
  float acc = 0.0f;
  for (int k0 = 0; k0 < DPER; k0 += KT) {
#pragma unroll
    for (int idx = tid; idx < RT * KT; idx += 256) {
      int rr = idx / KT, kk = idx % KT;
      int b = (rbase + rr) & 63;
      As[rr][kk] = xn[b * DET + k * DPER + k0 + kk];
    }
#pragma unroll
    for (int idx = tid; idx < KT * 32; idx += 256) {
      int kk = idx >> 5, c = idx & 31;
      Ws[kk][c] = W[(size_t)(k0 + kk) * 768 + colbase + c];
    }
    __syncthreads();
#pragma unroll 8
    for (int kk = 0; kk < KT; ++kk) acc += As[rg][kk] * Ws[kk][lane];
    __syncthreads();
  }
  int b = (rbase + rg) & 63;
  gates[b * 6144 + k * 768 + colbase + lane] = acc + bg_bias[k * 768 + colbase + lane];
}

// ---------------- small kernels (unchanged from R17) ----------------
__global__ void zero_initF(float* deter, float* stoch) {
  int i = blockIdx.x * 256 + threadIdx.x;
  for (int idx = i; idx < NB * DET; idx += gridDim.x * 256) deter[idx] = 0.0f;
  for (int idx = i; idx < NB * SDIM; idx += gridDim.x * 256) stoch[idx] = 0.0f;
}

__global__ __launch_bounds__(256) void norm_combF(
    const float* __restrict__ t0, const float* __restrict__ t1, const float* __restrict__ t2,
    const float* __restrict__ s0, const float* __restrict__ s1, const float* __restrict__ s2,
    float* __restrict__ comb)
{
  int b = blockIdx.x, tid = threadIdx.x;
  __shared__ float red[4];
  for (int part = 0; part < 3; ++part) {
    const float* src = part == 0 ? t0 : part == 1 ? t1 : t2;
    const float* sc  = part == 0 ? s0 : part == 1 ? s1 : s2;
    float v0 = src[b * 512 + tid];
    float v1 = src[b * 512 + 256 + tid];
    float ss = v0 * v0 + v1 * v1;
#pragma unroll
    for (int m = 1; m < 64; m <<= 1) ss += __shfl_xor(ss, m);
    if ((tid & 63) == 0) red[tid >> 6] = ss;
    __syncthreads();
    float rm = sqrtf((red[0] + red[1] + red[2] + red[3]) / 512.0f + 1e-8f);
    comb[b * 1536 + part * 512 + tid]       = silu_f(v0 / rm * sc[tid]);
    comb[b * 1536 + part * 512 + 256 + tid] = silu_f(v1 / rm * sc[256 + tid]);
    __syncthreads();
  }
}

__global__ __launch_bounds__(256) void norm_xnF(const float* __restrict__ bh,
                                                const float* __restrict__ snh,
                                                float* __restrict__ xn)
{
  int b = blockIdx.x, tid = threadIdx.x;
  __shared__ float red[4];
  float v[8]; float ss = 0.0f;
#pragma unroll
  for (int j = 0; j < 8; ++j) { v[j] = bh[b * DET + tid + 256 * j]; ss += v[j] * v[j]; }
#pragma unroll
  for (int m = 1; m < 64; m <<= 1) ss += __shfl_xor(ss, m);
  if ((tid & 63) == 0) red[tid >> 6] = ss;
  __syncthreads();
  float rm = sqrtf((red[0] + red[1] + red[2] + red[3]) / 2048.0f + 1e-8f);
#pragma unroll
  for (int j = 0; j < 8; ++j) {
    int o = tid + 256 * j;
    xn[b * DET + o] = silu_f(v[j] / rm * snh[o]);
  }
}

__global__ __launch_bounds__(256) void updF(const float* __restrict__ gates,
    float* __restrict__ deter, float* __restrict__ dout, int t)
{
  int b = blockIdx.x, tid = threadIdx.x;
#pragma unroll
  for (int j = 0; j < 8; ++j) {
    int d = tid + j * 256;
    float gr = gates[b * 6144 + d];
    float gc = gates[b * 6144 + 2048 + d];
    float gu = gates[b * 6144 + 4096 + d];
    float r = 1.0f / (1.0f + expf(-gr));
    float cnd = tanhf(r * gc);
    float u = 1.0f / (1.0f + expf(-(gu - 1.0f)));
    float nd = u * cnd + (1.0f - u) * deter[b * DET + d];
    deter[b * DET + d] = nd;
    dout[(size_t)(b * NT + t) * DET + d] = nd;
  }
}

__global__ __launch_bounds__(256) void q1_sampleF(
    const float* __restrict__ hq, const float* __restrict__ s_q0,
    const float* __restrict__ w_q1, const float* __restrict__ b_q1,
    float* __restrict__ stoch, float* __restrict__ out_s,
    float* __restrict__ out_post, int t)
{
  __shared__ float sh[8][512];
  __shared__ float ssr[8];
  const int tid = threadIdx.x;
  const int colbase = blockIdx.x * 128;
  const int rbase = blockIdx.y * 8;
  const int r_loc = tid >> 5, l32 = tid & 31;
  const int b = rbase + r_loc;
  {
    float ss = 0.0f;
#pragma unroll
    for (int j = 0; j < 16; ++j) {
      float v = hq[b * 512 + l32 + j * 32];
      sh[r_loc][l32 + j * 32] = v;
      ss += v * v;
    }
#pragma unroll
    for (int m = 1; m < 32; m <<= 1) ss += __shfl_xor(ss, m);
    if (l32 == 0) ssr[r_loc] = ss;
  }
  __syncthreads();
  {
    float rm = sqrtf(ssr[r_loc] / 512.0f + 1e-8f);
#pragma unroll
    for (int j = 0; j < 16; ++j) {
      int o = l32 + j * 32;
      sh[r_loc][o] = silu_f(sh[r_loc][o] / rm * s_q0[o]);
    }
  }
  __syncthreads();
  float acc[4] = {0, 0, 0, 0};
#pragma unroll 8
  for (int k = 0; k < 512; ++k) {
    float h = sh[r_loc][k];
#pragma unroll
    for (int j = 0; j < 4; ++j) acc[j] += h * w_q1[(size_t)k * 1024 + colbase + j * 32 + l32];
  }
#pragma unroll
  for (int j = 0; j < 4; ++j) {
    int col = colbase + j * 32 + l32;
    float logit = acc[j] + b_q1[col];
    out_post[(size_t)(b * NT + t) * SDIM + col] = logit;
    float m = logit;
#pragma unroll
    for (int mm = 1; mm < 32; mm <<= 1) m = fmaxf(m, __shfl_xor(m, mm));
    float e = expf(logit - m);
    float s = e;
#pragma unroll
    for (int mm = 1; mm < 32; mm <<= 1) s += __shfl_xor(s, mm);
    float p = 0.99f * (e / s) + 0.0003125f;
    float val = logf(p) + gumbel_f(t, b, col >> 5, l32);
    float bv = val; int bi = l32;
#pragma unroll
    for (int mm = 1; mm < 32; mm <<= 1) {
      float ov = __shfl_xor(bv, mm);
      int oi = __shfl_xor(bi, mm);
      if (ov > bv || (ov == bv && oi < bi)) { bv = ov; bi = oi; }
    }
    float ohv = (1.0f + p) - p;
    float oh = (bi == l32) ? ohv : 0.0f;
    stoch[b * SDIM + col] = oh;
    out_s[(size_t)(b * NT + t) * SDIM + col] = oh;
  }
}

// ---------------- f32 prior path (staged W) ----------------
template<int NACC>
__global__ __launch_bounds__(256) void gemm_k(const float* __restrict__ A, int lda,
    const float* __restrict__ W, int ldw, const float* __restrict__ bias,
    float* __restrict__ C, int ldc, int K)
{ gemm_bodyS<NACC>(A, lda, W, ldw, bias, C, ldc, K); }

__global__ __launch_bounds__(256) void norm_h(const float* __restrict__ raw,
                                              const float* __restrict__ scale,
                                              float* __restrict__ outp)
{
  int r = blockIdx.x, tid = threadIdx.x;
  __shared__ float red[4];
  float v0 = raw[(size_t)r * 512 + tid];
  float v1 = raw[(size_t)r * 512 + 256 + tid];
  float ss = v0 * v0 + v1 * v1;
#pragma unroll
  for (int m = 1; m < 64; m <<= 1) ss += __shfl_xor(ss, m);
  if ((tid & 63) == 0) red[tid >> 6] = ss;
  __syncthreads();
  float rm = sqrtf((red[0] + red[1] + red[2] + red[3]) / 512.0f + 1e-8f);
  outp[(size_t)r * 512 + tid]       = silu_f(v0 / rm * scale[tid]);
  outp[(size_t)r * 512 + 256 + tid] = silu_f(v1 / rm * scale[256 + tid]);
}

// ---------------- launch ----------------
extern "C" void kernel_launch(void* const* d_in, const int* in_sizes, int n_in,
                              void* d_out, int out_size, void* d_ws, size_t ws_size,
                              hipStream_t stream)
{
  const float* tokens     = (const float*)d_in[0];
  const float* actions    = (const float*)d_in[1];
  const float* w_in_deter = (const float*)d_in[3];
  const float* b_in_deter = (const float*)d_in[4];
  const float* w_in_stoch = (const float*)d_in[5];
  const float* b_in_stoch = (const float*)d_in[6];
  const float* w_in_act   = (const float*)d_in[7];
  const float* b_in_act   = (const float*)d_in[8];
  const float* s_n0 = (const float*)d_in[9];
  const float* s_n1 = (const float*)d_in[10];
  const float* s_n2 = (const float*)d_in[11];
  const float* w_blk_h = (const float*)d_in[12];
  const float* b_blk_h = (const float*)d_in[13];
  const float* s_nh = (const float*)d_in[14];
  const float* w_blk_g = (const float*)d_in[15];
  const float* b_blk_g = (const float*)d_in[16];
  const float* w_p0 = (const float*)d_in[17];
  const float* b_p0 = (const float*)d_in[18];
  const float* s_p0 = (const float*)d_in[19];
  const float* w_p1 = (const float*)d_in[20];
  const float* b_p1 = (const float*)d_in[21];
  const float* s_p1 = (const float*)d_in[22];
  const float* w_p2 = (const float*)d_in[23];
  const float* b_p2 = (const float*)d_in[24];
  const float* w_q0 = (const float*)d_in[25];
  const float* b_q0 = (const float*)d_in[26];
  const float* s_q0 = (const float*)d_in[27];
  const float* w_q1 = (const float*)d_in[28];
  const float* b_q1 = (const float*)d_in[29];

  float* ws = (float*)d_ws;
  float* deter = ws;                  // 131072
  float* stoch = deter + 131072;      // 65536
  float* t0b   = stoch + 65536;       // 32768
  float* t1b   = t0b + 32768;         // 32768
  float* t2b   = t1b + 32768;         // 32768
  float* comb  = t2b + 32768;         // 98304
  float* bh    = comb + 98304;        // 131072
  float* xn    = bh + 131072;         // 131072
  float* gates = xn + 131072;         // 393216
  float* hq    = gates + 393216;      // 32768
  float* hp_a  = ws;                  // prior overlay (loop state dead after loop)
  float* hp_b  = ws + 2097152;        // high-water 16.78 MB (proven available)

  float* outf = (float*)d_out;
  float* out_d    = outf;
  float* out_s    = outf + OS;
  float* out_pri  = outf + OPRI;
  float* out_post = outf + OPOST;

  zero_initF<<<dim3(256), dim3(256), 0, stream>>>(deter, stoch);

  for (int t = 0; t < NT; ++t) {
    GDf g0{deter, w_in_deter, b_in_deter, t0b, DET, DET, 0};
    GDf g1{stoch, w_in_stoch, b_in_stoch, t1b, SDIM, SDIM, 0};
    GDf g2{actions, w_in_act, b_in_act, t2b, ACTD, ACTD, 1};
    gemm_x3F<<<dim3(16, 8, 3), dim3(256), 0, stream>>>(g0, g1, g2, t);
    norm_combF<<<dim3(NB), dim3(256), 0, stream>>>(t0b, t1b, t2b, s_n0, s_n1, s_n2, comb);
    gemm_bhF<<<dim3(8, 64), dim3(256), 0, stream>>>(deter, comb, w_blk_h, b_blk_h, bh);
    norm_xnF<<<dim3(NB), dim3(256), 0, stream>>>(bh, s_nh, xn);
    gemm_bgF<<<dim3(24, 64), dim3(256), 0, stream>>>(xn, w_blk_g, b_blk_g, gates);
    updF<<<dim3(NB), dim3(256), 0, stream>>>(gates, deter, out_d, t);
    gemm_q0F<<<dim3(16, 8), dim3(256), 0, stream>>>(deter, tokens, w_q0, b_q0, hq, t);
    q1_sampleF<<<dim3(8, 8), dim3(256), 0, stream>>>(hq, s_q0, w_q1, b_q1,
        stoch, out_s, out_post, t);
  }

  // batched f32 prior from d_seq
  gemm_k<4><<<dim3(16, 128), dim3(256), 0, stream>>>(
      out_d, DET, w_p0, 512, b_p0, hp_a, 512, DET);
  norm_h<<<dim3(NB * NT), dim3(256), 0, stream>>>(hp_a, s_p0, hp_b);
  gemm_k<4><<<dim3(16, 128), dim3(256), 0, stream>>>(
      hp_b, 512, w_p1, 512, b_p1, hp_a, 512, 512);
  norm_h<<<dim3(NB * NT), dim3(256), 0, stream>>>(hp_a, s_p1, hp_b);
  gemm_k<4><<<dim3(32, 128), dim3(256), 0, stream>>>(
      hp_b, 512, w_p2, 1024, b_p2, out_pri, 1024, 512);
}